// Round 1
// baseline (1051.982 us; speedup 1.0000x reference)
//
#include <hip/hip_runtime.h>
#include <math.h>

#define TPB 256

__device__ __forceinline__ float lrelu(float a){ return a >= 0.f ? a : 0.2f*a; }

// ---------------- graph degree / CSR build ----------------

__global__ void k_init(int* deg, int* cnt, int* cursor, int N){
  int i = blockIdx.x*TPB + threadIdx.x;
  if(i < N){ deg[i] = 1; cnt[i] = 1; cursor[i] = 0; }  // 1 = self-loop
}

__global__ void k_count(const int* __restrict__ rows, const int* __restrict__ cols,
                        int* deg, int* cnt, int E){
  int e = blockIdx.x*TPB + threadIdx.x;
  if(e < E){
    atomicAdd(&deg[rows[e]], 1);   // degree over ROW (source) per reference gcn_norm
    atomicAdd(&cnt[cols[e]], 1);   // CSR counts over COL (target)
  }
}

__global__ void k_dinv(const int* __restrict__ deg, float* __restrict__ dinv, int N){
  int i = blockIdx.x*TPB + threadIdx.x;
  if(i < N) dinv[i] = 1.f / sqrtf((float)deg[i]);
}

// exclusive scan of cnt[0..N) into offs[0..N], 1024 elements per block
__global__ void k_scan_block(const int* __restrict__ cnt, int* __restrict__ bsum, int N){
  __shared__ int sdata[256];
  int base = blockIdx.x*1024 + threadIdx.x*4;
  int s = 0;
  #pragma unroll
  for(int i=0;i<4;i++){ int idx = base+i; if(idx < N) s += cnt[idx]; }
  sdata[threadIdx.x] = s; __syncthreads();
  for(int off=128; off>0; off>>=1){
    if(threadIdx.x < off) sdata[threadIdx.x] += sdata[threadIdx.x+off];
    __syncthreads();
  }
  if(threadIdx.x == 0) bsum[blockIdx.x] = sdata[0];
}

__global__ void k_scan_bsum(int* bsum, int NB){
  __shared__ int s[256];
  int t = threadIdx.x;
  int v = (t < NB) ? bsum[t] : 0;
  s[t] = v; __syncthreads();
  for(int off=1; off<256; off<<=1){
    int add = (t >= off) ? s[t-off] : 0;
    __syncthreads();
    s[t] += add;
    __syncthreads();
  }
  if(t < NB) bsum[t] = s[t] - v;   // exclusive
}

__global__ void k_scan_write(const int* __restrict__ cnt, const int* __restrict__ bsum,
                             int* __restrict__ offs, int N){
  __shared__ int sdata[256];
  int t = threadIdx.x;
  int base = blockIdx.x*1024 + t*4;
  int v[4]; int s = 0;
  #pragma unroll
  for(int i=0;i<4;i++){ int idx = base+i; v[i] = (idx < N) ? cnt[idx] : 0; s += v[i]; }
  sdata[t] = s; __syncthreads();
  int mine = s;
  for(int off=1; off<256; off<<=1){
    int add = (t >= off) ? sdata[t-off] : 0;
    __syncthreads();
    sdata[t] += add;
    __syncthreads();
  }
  int run = sdata[t] - mine + bsum[blockIdx.x];
  #pragma unroll
  for(int i=0;i<4;i++){
    int idx = base+i;
    if(idx < N){
      offs[idx] = run;
      run += v[i];
      if(idx == N-1) offs[N] = run;
    }
  }
}

__global__ void k_fill(const int* __restrict__ rows, const int* __restrict__ cols,
                       const int* __restrict__ offs, int* cursor,
                       int* __restrict__ csr_src, int E, int N){
  int e = blockIdx.x*TPB + threadIdx.x;
  int tot = E + N;
  if(e >= tot) return;
  int r, c;
  if(e < E){ r = rows[e]; c = cols[e]; } else { r = c = e - E; }
  int pos = offs[c] + atomicAdd(&cursor[c], 1);
  csr_src[pos] = r;
}

// ---------------- layer 1 GEMM: xt1 = x @ W1   (N x 256) @ (256 x 128) ----------------

#define G1_ROWS 16
__global__ __launch_bounds__(64) void k_gemm1(const float* __restrict__ x,
                                              const float* __restrict__ W,
                                              float* __restrict__ xt, int N){
  __shared__ float xs[G1_ROWS*256];
  int n0 = blockIdx.x * G1_ROWS;
  int t = threadIdx.x;            // 0..63
  // stage 16 rows x 256 cols: 1024 float4, 16 per thread
  #pragma unroll
  for(int i=0;i<16;i++){
    int idx = t + 64*i;           // float4 index
    int r = idx >> 6, k4 = idx & 63;
    int n = n0 + r;
    float4 v = make_float4(0.f,0.f,0.f,0.f);
    if(n < N) v = ((const float4*)x)[(size_t)n*64 + k4];
    ((float4*)xs)[idx] = v;
  }
  __syncthreads();
  float acc0[G1_ROWS], acc1[G1_ROWS];
  #pragma unroll
  for(int r=0;r<G1_ROWS;r++){ acc0[r]=0.f; acc1[r]=0.f; }
  int c0 = t, c1 = t + 64;
  for(int k=0;k<256;k+=4){
    float w00=W[(k  )*128+c0], w01=W[(k  )*128+c1];
    float w10=W[(k+1)*128+c0], w11=W[(k+1)*128+c1];
    float w20=W[(k+2)*128+c0], w21=W[(k+2)*128+c1];
    float w30=W[(k+3)*128+c0], w31=W[(k+3)*128+c1];
    #pragma unroll
    for(int r=0;r<G1_ROWS;r++){
      float4 xv = *((const float4*)&xs[r*256+k]);
      acc0[r] += xv.x*w00 + xv.y*w10 + xv.z*w20 + xv.w*w30;
      acc1[r] += xv.x*w01 + xv.y*w11 + xv.z*w21 + xv.w*w31;
    }
  }
  #pragma unroll
  for(int r=0;r<G1_ROWS;r++){
    int n = n0 + r;
    if(n < N){ xt[(size_t)n*128+c0] = acc0[r]; xt[(size_t)n*128+c1] = acc1[r]; }
  }
}

// per-node attention scalars, layer 1: s_l[n,h], s_r[n,h]
__global__ void k_sr1(const float* __restrict__ xt, const float* __restrict__ att1,
                      float* __restrict__ sl, float* __restrict__ sr, int N){
  int i = blockIdx.x*TPB + threadIdx.x;   // i = n*4 + h
  if(i >= N*4) return;
  int n = i >> 2, hh = i & 3;
  const float* xp = xt + (size_t)n*128 + hh*32;
  const float* al = att1 + hh*64;
  const float* ar = al + 32;
  float a = 0.f, b = 0.f;
  #pragma unroll
  for(int c=0;c<32;c++){ float v = xp[c]; a += v*al[c]; b += v*ar[c]; }
  sl[i] = a; sr[i] = b;
}

// ---------------- layer 1 aggregation: one wave per target node ----------------

__global__ __launch_bounds__(64) void k_agg1(const int* __restrict__ offs, const int* __restrict__ srcs,
    const float* __restrict__ sl, const float* __restrict__ sr, const float* __restrict__ dinv,
    const float* __restrict__ xt, const float* __restrict__ b1, float* __restrict__ h, int N){
  int n = blockIdx.x;
  if(n >= N) return;
  int lane = threadIdx.x;
  int beg = offs[n], end = offs[n+1];
  float4 sln = *((const float4*)(sl + (size_t)n*4));
  float din = dinv[n];
  // pass 1: per-head max of leaky-relu(alpha)
  float4 m = make_float4(-1e30f,-1e30f,-1e30f,-1e30f);
  for(int j=beg; j<end; j++){
    int s = srcs[j];
    float4 a = *((const float4*)(sr + (size_t)s*4));
    float a0 = lrelu(sln.x + a.x), a1 = lrelu(sln.y + a.y);
    float a2 = lrelu(sln.z + a.z), a3 = lrelu(sln.w + a.w);
    m.x = fmaxf(m.x, a0); m.y = fmaxf(m.y, a1);
    m.z = fmaxf(m.z, a2); m.w = fmaxf(m.w, a3);
  }
  // pass 2: denom + weighted feature accumulation
  float4 den = make_float4(0.f,0.f,0.f,0.f);
  float acc0 = 0.f, acc1 = 0.f;
  for(int j=beg; j<end; j++){
    int s = srcs[j];
    float4 a = *((const float4*)(sr + (size_t)s*4));
    float e0 = expf(lrelu(sln.x + a.x) - m.x);
    float e1 = expf(lrelu(sln.y + a.y) - m.y);
    float e2 = expf(lrelu(sln.z + a.z) - m.z);
    float e3 = expf(lrelu(sln.w + a.w) - m.w);
    den.x += e0; den.y += e1; den.z += e2; den.w += e3;
    float w = din * dinv[s];
    float wa = w * ((lane < 32) ? e0 : e1);   // channel lane   -> head lane>>5 (0/1)
    float wb = w * ((lane < 32) ? e2 : e3);   // channel lane+64-> head 2/3
    const float* xr = xt + (size_t)s*128;
    acc0 += wa * xr[lane];
    acc1 += wb * xr[64 + lane];
  }
  float d0 = (lane < 32) ? den.x : den.y;
  float d1 = (lane < 32) ? den.z : den.w;
  float o0 = acc0/(d0 + 1e-16f) + b1[lane];
  float o1 = acc1/(d1 + 1e-16f) + b1[64+lane];
  h[(size_t)n*128 + lane]      = o0 > 0.f ? o0 : 0.f;   // fused ReLU
  h[(size_t)n*128 + 64 + lane] = o1 > 0.f ? o1 : 0.f;
}

// ---------------- layer 2 GEMM (128->16) + attention scalars fused ----------------

__global__ __launch_bounds__(256) void k_gemm2(const float* __restrict__ hmat, const float* __restrict__ W2,
    const float* __restrict__ att2, float* __restrict__ xt2,
    float* __restrict__ sl2, float* __restrict__ sr2, int N){
  __shared__ float hs[16*132];
  __shared__ float ws[16*132];   // transposed, padded: ws[c*132+k]
  __shared__ float xs[16*16];
  int t = threadIdx.x;
  int n0 = blockIdx.x * 16;
  // load W2 (128x16) transposed into ws
  #pragma unroll
  for(int i=0;i<8;i++){
    int idx = t + 256*i;         // 0..2047
    int k = idx >> 4, c = idx & 15;
    ws[c*132 + k] = W2[idx];
  }
  // load 16 h rows (128 each), padded stride 132
  #pragma unroll
  for(int i=0;i<2;i++){
    int idx = t + 256*i;         // float4 idx 0..511
    int r = idx >> 5, k4 = idx & 31;
    int n = n0 + r;
    float4 v = make_float4(0.f,0.f,0.f,0.f);
    if(n < N) v = ((const float4*)hmat)[(size_t)n*32 + k4];
    *((float4*)&hs[r*132 + k4*4]) = v;
  }
  __syncthreads();
  int r = t >> 4, c = t & 15;
  float acc = 0.f;
  for(int k=0;k<128;k+=4){
    float4 hv = *((const float4*)&hs[r*132+k]);
    float4 wv = *((const float4*)&ws[c*132+k]);
    acc += hv.x*wv.x + hv.y*wv.y + hv.z*wv.z + hv.w*wv.w;
  }
  int n = n0 + r;
  if(n < N) xt2[(size_t)n*16 + c] = acc;
  xs[r*16 + c] = acc;
  __syncthreads();
  if(t < 16){
    int nn = n0 + t;
    if(nn < N){
      float a = 0.f, b = 0.f;
      #pragma unroll
      for(int cc=0;cc<16;cc++){ float v = xs[t*16+cc]; a += v*att2[cc]; b += v*att2[16+cc]; }
      sl2[nn] = a; sr2[nn] = b;
    }
  }
}

// ---------------- layer 2 aggregation ----------------

__global__ __launch_bounds__(64) void k_agg2(const int* __restrict__ offs, const int* __restrict__ srcs,
    const float* __restrict__ sl2, const float* __restrict__ sr2, const float* __restrict__ dinv,
    const float* __restrict__ xt2, const float* __restrict__ b2, float* __restrict__ out, int N){
  int n = blockIdx.x;
  if(n >= N) return;
  int lane = threadIdx.x;
  int beg = offs[n], end = offs[n+1];
  float sln = sl2[n];
  float din = dinv[n];
  float m = -1e30f;
  for(int j=beg; j<end; j++){
    float a = lrelu(sln + sr2[srcs[j]]);
    m = fmaxf(m, a);
  }
  float den = 0.f, acc = 0.f;
  for(int j=beg; j<end; j++){
    int s = srcs[j];
    float e = expf(lrelu(sln + sr2[s]) - m);
    den += e;
    float xv = (lane < 16) ? xt2[(size_t)s*16 + lane] : 0.f;
    acc += din * dinv[s] * e * xv;
  }
  if(lane < 16) out[(size_t)n*16 + lane] = acc/(den + 1e-16f) + b2[lane];
}

// ---------------- host launch ----------------

extern "C" void kernel_launch(void* const* d_in, const int* in_sizes, int n_in,
                              void* d_out, int out_size, void* d_ws, size_t ws_size,
                              hipStream_t stream){
  const float* x    = (const float*)d_in[0];
  const int*   ei   = (const int*)d_in[1];
  const float* W1   = (const float*)d_in[2];
  const float* att1 = (const float*)d_in[3];
  const float* b1   = (const float*)d_in[4];
  const float* W2   = (const float*)d_in[5];
  const float* att2 = (const float*)d_in[6];
  const float* b2   = (const float*)d_in[7];
  int N = in_sizes[0] / 256;
  int E = in_sizes[1] / 2;
  const int* rows = ei;
  const int* cols = ei + E;
  float* out = (float*)d_out;

  char* p = (char*)d_ws;
  auto alloc = [&](size_t bytes)->void*{ void* q = p; p += (bytes + 255) & ~(size_t)255; return q; };
  int*   deg    = (int*)alloc((size_t)N*4);
  int*   cnt    = (int*)alloc((size_t)N*4);
  int*   cursor = (int*)alloc((size_t)N*4);
  int*   offs   = (int*)alloc((size_t)(N+1)*4);
  int*   bsum   = (int*)alloc(256*4);
  int*   csr    = (int*)alloc((size_t)(E+N)*4);
  float* dinv   = (float*)alloc((size_t)N*4);
  float* xt1    = (float*)alloc((size_t)N*128*4);
  float* sl1    = (float*)alloc((size_t)N*16);
  float* sr1    = (float*)alloc((size_t)N*16);
  float* hbuf   = (float*)alloc((size_t)N*128*4);
  float* xt2    = (float*)alloc((size_t)N*16*4);
  float* sl2    = (float*)alloc((size_t)N*4);
  float* sr2    = (float*)alloc((size_t)N*4);

  int gN   = (N + TPB - 1) / TPB;
  int gE   = (E + TPB - 1) / TPB;
  int gEN  = (E + N + TPB - 1) / TPB;
  int NB   = (N + 1023) / 1024;

  k_init<<<gN, TPB, 0, stream>>>(deg, cnt, cursor, N);
  k_count<<<gE, TPB, 0, stream>>>(rows, cols, deg, cnt, E);
  k_dinv<<<gN, TPB, 0, stream>>>(deg, dinv, N);
  k_scan_block<<<NB, 256, 0, stream>>>(cnt, bsum, N);
  k_scan_bsum<<<1, 256, 0, stream>>>(bsum, NB);
  k_scan_write<<<NB, 256, 0, stream>>>(cnt, bsum, offs, N);
  k_fill<<<gEN, TPB, 0, stream>>>(rows, cols, offs, cursor, csr, E, N);

  k_gemm1<<<(N + G1_ROWS - 1)/G1_ROWS, 64, 0, stream>>>(x, W1, xt1, N);
  k_sr1<<<(4*N + TPB - 1)/TPB, TPB, 0, stream>>>(xt1, att1, sl1, sr1, N);
  k_agg1<<<N, 64, 0, stream>>>(offs, csr, sl1, sr1, dinv, xt1, b1, hbuf, N);

  k_gemm2<<<(N + 15)/16, 256, 0, stream>>>(hbuf, W2, att2, xt2, sl2, sr2, N);
  k_agg2<<<N, 64, 0, stream>>>(offs, csr, sl2, sr2, dinv, xt2, b2, out, N);
}

// Round 2
// 774.317 us; speedup vs baseline: 1.3586x; 1.3586x over previous
//
#include <hip/hip_runtime.h>
#include <math.h>

#define TPB 256

__device__ __forceinline__ float lrelu(float a){ return a >= 0.f ? a : 0.2f*a; }

// ---------------- graph degree / CSR build ----------------

__global__ void k_init(int* deg, int* cnt, int* cursor, int N){
  int i = blockIdx.x*TPB + threadIdx.x;
  if(i < N){ deg[i] = 1; cnt[i] = 1; cursor[i] = 0; }  // 1 = self-loop
}

__global__ void k_count(const int* __restrict__ rows, const int* __restrict__ cols,
                        int* deg, int* cnt, int E){
  int e = blockIdx.x*TPB + threadIdx.x;
  if(e < E){
    atomicAdd(&deg[rows[e]], 1);   // degree over ROW (source) per reference gcn_norm
    atomicAdd(&cnt[cols[e]], 1);   // CSR counts over COL (target)
  }
}

__global__ void k_dinv(const int* __restrict__ deg, float* __restrict__ dinv, int N){
  int i = blockIdx.x*TPB + threadIdx.x;
  if(i < N) dinv[i] = 1.f / sqrtf((float)deg[i]);
}

// exclusive scan of cnt[0..N) into offs[0..N], 1024 elements per block
__global__ void k_scan_block(const int* __restrict__ cnt, int* __restrict__ bsum, int N){
  __shared__ int sdata[256];
  int base = blockIdx.x*1024 + threadIdx.x*4;
  int s = 0;
  #pragma unroll
  for(int i=0;i<4;i++){ int idx = base+i; if(idx < N) s += cnt[idx]; }
  sdata[threadIdx.x] = s; __syncthreads();
  for(int off=128; off>0; off>>=1){
    if(threadIdx.x < off) sdata[threadIdx.x] += sdata[threadIdx.x+off];
    __syncthreads();
  }
  if(threadIdx.x == 0) bsum[blockIdx.x] = sdata[0];
}

__global__ void k_scan_bsum(int* bsum, int NB){
  __shared__ int s[256];
  int t = threadIdx.x;
  int v = (t < NB) ? bsum[t] : 0;
  s[t] = v; __syncthreads();
  for(int off=1; off<256; off<<=1){
    int add = (t >= off) ? s[t-off] : 0;
    __syncthreads();
    s[t] += add;
    __syncthreads();
  }
  if(t < NB) bsum[t] = s[t] - v;   // exclusive
}

__global__ void k_scan_write(const int* __restrict__ cnt, const int* __restrict__ bsum,
                             int* __restrict__ offs, int N){
  __shared__ int sdata[256];
  int t = threadIdx.x;
  int base = blockIdx.x*1024 + t*4;
  int v[4]; int s = 0;
  #pragma unroll
  for(int i=0;i<4;i++){ int idx = base+i; v[i] = (idx < N) ? cnt[idx] : 0; s += v[i]; }
  sdata[t] = s; __syncthreads();
  int mine = s;
  for(int off=1; off<256; off<<=1){
    int add = (t >= off) ? sdata[t-off] : 0;
    __syncthreads();
    sdata[t] += add;
    __syncthreads();
  }
  int run = sdata[t] - mine + bsum[blockIdx.x];
  #pragma unroll
  for(int i=0;i<4;i++){
    int idx = base+i;
    if(idx < N){
      offs[idx] = run;
      run += v[i];
      if(idx == N-1) offs[N] = run;
    }
  }
}

__global__ void k_fill(const int* __restrict__ rows, const int* __restrict__ cols,
                       const int* __restrict__ offs, int* cursor,
                       int* __restrict__ csr_src, int E, int N){
  int e = blockIdx.x*TPB + threadIdx.x;
  int tot = E + N;
  if(e >= tot) return;
  int r, c;
  if(e < E){ r = rows[e]; c = cols[e]; } else { r = c = e - E; }
  int pos = offs[c] + atomicAdd(&cursor[c], 1);
  csr_src[pos] = r;
}

// ---------------- layer 1 GEMM: xt1 = x @ W1   (N x 256) @ (256 x 128) ----------------

#define G1_ROWS 16
__global__ __launch_bounds__(64) void k_gemm1(const float* __restrict__ x,
                                              const float* __restrict__ W,
                                              float* __restrict__ xt, int N){
  __shared__ float xs[G1_ROWS*256];
  int n0 = blockIdx.x * G1_ROWS;
  int t = threadIdx.x;            // 0..63
  #pragma unroll
  for(int i=0;i<16;i++){
    int idx = t + 64*i;           // float4 index
    int r = idx >> 6, k4 = idx & 63;
    int n = n0 + r;
    float4 v = make_float4(0.f,0.f,0.f,0.f);
    if(n < N) v = ((const float4*)x)[(size_t)n*64 + k4];
    ((float4*)xs)[idx] = v;
  }
  __syncthreads();
  float acc0[G1_ROWS], acc1[G1_ROWS];
  #pragma unroll
  for(int r=0;r<G1_ROWS;r++){ acc0[r]=0.f; acc1[r]=0.f; }
  int c0 = t, c1 = t + 64;
  for(int k=0;k<256;k+=4){
    float w00=W[(k  )*128+c0], w01=W[(k  )*128+c1];
    float w10=W[(k+1)*128+c0], w11=W[(k+1)*128+c1];
    float w20=W[(k+2)*128+c0], w21=W[(k+2)*128+c1];
    float w30=W[(k+3)*128+c0], w31=W[(k+3)*128+c1];
    #pragma unroll
    for(int r=0;r<G1_ROWS;r++){
      float4 xv = *((const float4*)&xs[r*256+k]);
      acc0[r] += xv.x*w00 + xv.y*w10 + xv.z*w20 + xv.w*w30;
      acc1[r] += xv.x*w01 + xv.y*w11 + xv.z*w21 + xv.w*w31;
    }
  }
  #pragma unroll
  for(int r=0;r<G1_ROWS;r++){
    int n = n0 + r;
    if(n < N){ xt[(size_t)n*128+c0] = acc0[r]; xt[(size_t)n*128+c1] = acc1[r]; }
  }
}

// per-node attention scalars, layer 1: s_l[n,h], s_r[n,h]
__global__ void k_sr1(const float* __restrict__ xt, const float* __restrict__ att1,
                      float* __restrict__ sl, float* __restrict__ sr, int N){
  int i = blockIdx.x*TPB + threadIdx.x;   // i = n*4 + h
  if(i >= N*4) return;
  int n = i >> 2, hh = i & 3;
  const float* xp = xt + (size_t)n*128 + hh*32;
  const float* al = att1 + hh*64;
  const float* ar = al + 32;
  float a = 0.f, b = 0.f;
  #pragma unroll
  for(int c=0;c<32;c++){ float v = xp[c]; a += v*al[c]; b += v*ar[c]; }
  sl[i] = a; sr[i] = b;
}

// ---------------- layer 1 aggregation: one wave per target node ----------------
// Per-edge scalar work (alpha, exp) distributed across lanes; 64-edge chunks
// staged through LDS; feature gather uses scalar-base loads (readfirstlane).

__global__ __launch_bounds__(64) void k_agg1(const int* __restrict__ offs, const int* __restrict__ srcs,
    const float* __restrict__ sl, const float* __restrict__ sr, const float* __restrict__ dinv,
    const float* __restrict__ xt, const float* __restrict__ b1, float* __restrict__ h, int N){
  __shared__ int   s_sh[64];
  __shared__ float w_sh[64*4];
  int n = blockIdx.x;
  if(n >= N) return;
  int lane = threadIdx.x;
  int beg = offs[n], end = offs[n+1];
  float4 sln = *((const float4*)(sl + (size_t)n*4));
  // pass 1: per-lane max over its edge subset, then wave reduce
  float m0=-1e30f,m1=-1e30f,m2=-1e30f,m3=-1e30f;
  for(int j=beg+lane; j<end; j+=64){
    int s = srcs[j];
    float4 a = *((const float4*)(sr + (size_t)s*4));
    m0 = fmaxf(m0, lrelu(sln.x + a.x));
    m1 = fmaxf(m1, lrelu(sln.y + a.y));
    m2 = fmaxf(m2, lrelu(sln.z + a.z));
    m3 = fmaxf(m3, lrelu(sln.w + a.w));
  }
  #pragma unroll
  for(int o=32;o>0;o>>=1){
    m0 = fmaxf(m0, __shfl_xor(m0,o));
    m1 = fmaxf(m1, __shfl_xor(m1,o));
    m2 = fmaxf(m2, __shfl_xor(m2,o));
    m3 = fmaxf(m3, __shfl_xor(m3,o));
  }
  int h0 = lane >> 5;           // which head within the pair
  float den0=0.f,den1=0.f,den2=0.f,den3=0.f;
  float acc0=0.f, acc1=0.f;
  for(int c0=beg; c0<end; c0+=64){
    int cnt = min(64, end-c0);
    int j = c0 + lane;
    float e0=0.f,e1=0.f,e2=0.f,e3=0.f, wd=0.f; int s=0;
    if(j<end){
      s = srcs[j];
      float4 a = *((const float4*)(sr + (size_t)s*4));
      e0 = __expf(lrelu(sln.x + a.x) - m0);
      e1 = __expf(lrelu(sln.y + a.y) - m1);
      e2 = __expf(lrelu(sln.z + a.z) - m2);
      e3 = __expf(lrelu(sln.w + a.w) - m3);
      wd = dinv[s];
    }
    den0+=e0; den1+=e1; den2+=e2; den3+=e3;
    s_sh[lane] = s;
    w_sh[lane*4+0] = wd*e0;     // order (e0,e2,e1,e3): lane reads float2 at 4k+2*h0
    w_sh[lane*4+1] = wd*e2;
    w_sh[lane*4+2] = wd*e1;
    w_sh[lane*4+3] = wd*e3;
    __syncthreads();
    for(int k=0;k<cnt;k++){
      int sk = __builtin_amdgcn_readfirstlane(s_sh[k]);
      float2 wv = *((const float2*)&w_sh[k*4 + h0*2]);
      const float* xr = xt + (size_t)sk*128;
      acc0 += wv.x * xr[lane];
      acc1 += wv.y * xr[64+lane];
    }
    __syncthreads();
  }
  #pragma unroll
  for(int o=32;o>0;o>>=1){
    den0 += __shfl_xor(den0,o);
    den1 += __shfl_xor(den1,o);
    den2 += __shfl_xor(den2,o);
    den3 += __shfl_xor(den3,o);
  }
  float din = dinv[n];
  float d0 = (h0==0) ? den0 : den1;
  float d1 = (h0==0) ? den2 : den3;
  float o0 = din*acc0/(d0 + 1e-16f) + b1[lane];
  float o1 = din*acc1/(d1 + 1e-16f) + b1[64+lane];
  h[(size_t)n*128 + lane]      = o0 > 0.f ? o0 : 0.f;   // fused ReLU
  h[(size_t)n*128 + 64 + lane] = o1 > 0.f ? o1 : 0.f;
}

// ---------------- layer 2 GEMM (128->16) + attention scalars fused ----------------

__global__ __launch_bounds__(256) void k_gemm2(const float* __restrict__ hmat, const float* __restrict__ W2,
    const float* __restrict__ att2, float* __restrict__ xt2,
    float* __restrict__ sl2, float* __restrict__ sr2, int N){
  __shared__ float hs[16*132];
  __shared__ float ws[16*132];   // transposed, padded: ws[c*132+k]
  __shared__ float xs[16*16];
  int t = threadIdx.x;
  int n0 = blockIdx.x * 16;
  #pragma unroll
  for(int i=0;i<8;i++){
    int idx = t + 256*i;         // 0..2047
    int k = idx >> 4, c = idx & 15;
    ws[c*132 + k] = W2[idx];
  }
  #pragma unroll
  for(int i=0;i<2;i++){
    int idx = t + 256*i;         // float4 idx 0..511
    int r = idx >> 5, k4 = idx & 31;
    int n = n0 + r;
    float4 v = make_float4(0.f,0.f,0.f,0.f);
    if(n < N) v = ((const float4*)hmat)[(size_t)n*32 + k4];
    *((float4*)&hs[r*132 + k4*4]) = v;
  }
  __syncthreads();
  int r = t >> 4, c = t & 15;
  float acc = 0.f;
  for(int k=0;k<128;k+=4){
    float4 hv = *((const float4*)&hs[r*132+k]);
    float4 wv = *((const float4*)&ws[c*132+k]);
    acc += hv.x*wv.x + hv.y*wv.y + hv.z*wv.z + hv.w*wv.w;
  }
  int n = n0 + r;
  if(n < N) xt2[(size_t)n*16 + c] = acc;
  xs[r*16 + c] = acc;
  __syncthreads();
  if(t < 16){
    int nn = n0 + t;
    if(nn < N){
      float a = 0.f, b = 0.f;
      #pragma unroll
      for(int cc=0;cc<16;cc++){ float v = xs[t*16+cc]; a += v*att2[cc]; b += v*att2[16+cc]; }
      sl2[nn] = a; sr2[nn] = b;
    }
  }
}

// ---------------- layer 2 aggregation ----------------
// 4 edges x 16 channels per iteration; cross-group shuffle reduce.

__global__ __launch_bounds__(64) void k_agg2(const int* __restrict__ offs, const int* __restrict__ srcs,
    const float* __restrict__ sl2, const float* __restrict__ sr2, const float* __restrict__ dinv,
    const float* __restrict__ xt2, const float* __restrict__ b2, float* __restrict__ out, int N){
  __shared__ int   s_sh[64];
  __shared__ float w_sh[64];
  int n = blockIdx.x;
  if(n >= N) return;
  int lane = threadIdx.x;
  int beg = offs[n], end = offs[n+1];
  float sln = sl2[n];
  float m = -1e30f;
  for(int j=beg+lane; j<end; j+=64)
    m = fmaxf(m, lrelu(sln + sr2[srcs[j]]));
  #pragma unroll
  for(int o=32;o>0;o>>=1) m = fmaxf(m, __shfl_xor(m,o));
  float den = 0.f, acc = 0.f;
  int grp = lane >> 4, ch = lane & 15;
  for(int c0=beg; c0<end; c0+=64){
    int cnt = min(64, end-c0);
    int j = c0 + lane;
    float e=0.f, wd=0.f; int s=0;
    if(j<end){
      s = srcs[j];
      e = __expf(lrelu(sln + sr2[s]) - m);
      wd = dinv[s];
    }
    den += e;
    s_sh[lane] = s;
    w_sh[lane] = wd*e;
    __syncthreads();
    for(int k=0;k<cnt;k+=4){
      int kk = k + grp;
      if(kk < cnt){
        int sk = s_sh[kk];
        float wk = w_sh[kk];
        acc += wk * xt2[(size_t)sk*16 + ch];
      }
    }
    __syncthreads();
  }
  #pragma unroll
  for(int o=32;o>0;o>>=1) den += __shfl_xor(den,o);
  acc += __shfl_xor(acc,16);
  acc += __shfl_xor(acc,32);
  if(lane < 16) out[(size_t)n*16 + lane] = dinv[n]*acc/(den + 1e-16f) + b2[lane];
}

// ---------------- host launch ----------------

extern "C" void kernel_launch(void* const* d_in, const int* in_sizes, int n_in,
                              void* d_out, int out_size, void* d_ws, size_t ws_size,
                              hipStream_t stream){
  const float* x    = (const float*)d_in[0];
  const int*   ei   = (const int*)d_in[1];
  const float* W1   = (const float*)d_in[2];
  const float* att1 = (const float*)d_in[3];
  const float* b1   = (const float*)d_in[4];
  const float* W2   = (const float*)d_in[5];
  const float* att2 = (const float*)d_in[6];
  const float* b2   = (const float*)d_in[7];
  int N = in_sizes[0] / 256;
  int E = in_sizes[1] / 2;
  const int* rows = ei;
  const int* cols = ei + E;
  float* out = (float*)d_out;

  char* p = (char*)d_ws;
  auto alloc = [&](size_t bytes)->void*{ void* q = p; p += (bytes + 255) & ~(size_t)255; return q; };
  int*   deg    = (int*)alloc((size_t)N*4);
  int*   cnt    = (int*)alloc((size_t)N*4);
  int*   cursor = (int*)alloc((size_t)N*4);
  int*   offs   = (int*)alloc((size_t)(N+1)*4);
  int*   bsum   = (int*)alloc(256*4);
  int*   csr    = (int*)alloc((size_t)(E+N)*4);
  float* dinv   = (float*)alloc((size_t)N*4);
  float* xt1    = (float*)alloc((size_t)N*128*4);
  float* sl1    = (float*)alloc((size_t)N*16);
  float* sr1    = (float*)alloc((size_t)N*16);
  float* hbuf   = (float*)alloc((size_t)N*128*4);
  float* xt2    = (float*)alloc((size_t)N*16*4);
  float* sl2    = (float*)alloc((size_t)N*4);
  float* sr2    = (float*)alloc((size_t)N*4);

  int gN   = (N + TPB - 1) / TPB;
  int gE   = (E + TPB - 1) / TPB;
  int gEN  = (E + N + TPB - 1) / TPB;
  int NB   = (N + 1023) / 1024;

  k_init<<<gN, TPB, 0, stream>>>(deg, cnt, cursor, N);
  k_count<<<gE, TPB, 0, stream>>>(rows, cols, deg, cnt, E);
  k_dinv<<<gN, TPB, 0, stream>>>(deg, dinv, N);
  k_scan_block<<<NB, 256, 0, stream>>>(cnt, bsum, N);
  k_scan_bsum<<<1, 256, 0, stream>>>(bsum, NB);
  k_scan_write<<<NB, 256, 0, stream>>>(cnt, bsum, offs, N);
  k_fill<<<gEN, TPB, 0, stream>>>(rows, cols, offs, cursor, csr, E, N);

  k_gemm1<<<(N + G1_ROWS - 1)/G1_ROWS, 64, 0, stream>>>(x, W1, xt1, N);
  k_sr1<<<(4*N + TPB - 1)/TPB, TPB, 0, stream>>>(xt1, att1, sl1, sr1, N);
  k_agg1<<<N, 64, 0, stream>>>(offs, csr, sl1, sr1, dinv, xt1, b1, hbuf, N);

  k_gemm2<<<(N + 15)/16, 256, 0, stream>>>(hbuf, W2, att2, xt2, sl2, sr2, N);
  k_agg2<<<N, 64, 0, stream>>>(offs, csr, sl2, sr2, dinv, xt2, b2, out, N);
}

// Round 3
// 764.784 us; speedup vs baseline: 1.3755x; 1.0125x over previous
//
#include <hip/hip_runtime.h>
#include <math.h>

#define TPB 256

__device__ __forceinline__ float lrelu(float a){ return a >= 0.f ? a : 0.2f*a; }

// ---------------- graph degree / CSR build ----------------

__global__ void k_init(int* deg, int* cnt, int* cursor, int N){
  int i = blockIdx.x*TPB + threadIdx.x;
  if(i < N){ deg[i] = 1; cnt[i] = 1; cursor[i] = 0; }  // 1 = self-loop
}

__global__ void k_count(const int* __restrict__ rows, const int* __restrict__ cols,
                        int* deg, int* cnt, int E){
  int e = blockIdx.x*TPB + threadIdx.x;
  if(e < E){
    atomicAdd(&deg[rows[e]], 1);   // degree over ROW (source) per reference gcn_norm
    atomicAdd(&cnt[cols[e]], 1);   // CSR counts over COL (target)
  }
}

__global__ void k_dinv(const int* __restrict__ deg, float* __restrict__ dinv, int N){
  int i = blockIdx.x*TPB + threadIdx.x;
  if(i < N) dinv[i] = 1.f / sqrtf((float)deg[i]);
}

// exclusive scan of cnt[0..N) into offs[0..N], 1024 elements per block
__global__ void k_scan_block(const int* __restrict__ cnt, int* __restrict__ bsum, int N){
  __shared__ int sdata[256];
  int base = blockIdx.x*1024 + threadIdx.x*4;
  int s = 0;
  #pragma unroll
  for(int i=0;i<4;i++){ int idx = base+i; if(idx < N) s += cnt[idx]; }
  sdata[threadIdx.x] = s; __syncthreads();
  for(int off=128; off>0; off>>=1){
    if(threadIdx.x < off) sdata[threadIdx.x] += sdata[threadIdx.x+off];
    __syncthreads();
  }
  if(threadIdx.x == 0) bsum[blockIdx.x] = sdata[0];
}

__global__ void k_scan_bsum(int* bsum, int NB){
  __shared__ int s[256];
  int t = threadIdx.x;
  int v = (t < NB) ? bsum[t] : 0;
  s[t] = v; __syncthreads();
  for(int off=1; off<256; off<<=1){
    int add = (t >= off) ? s[t-off] : 0;
    __syncthreads();
    s[t] += add;
    __syncthreads();
  }
  if(t < NB) bsum[t] = s[t] - v;   // exclusive
}

__global__ void k_scan_write(const int* __restrict__ cnt, const int* __restrict__ bsum,
                             int* __restrict__ offs, int N){
  __shared__ int sdata[256];
  int t = threadIdx.x;
  int base = blockIdx.x*1024 + t*4;
  int v[4]; int s = 0;
  #pragma unroll
  for(int i=0;i<4;i++){ int idx = base+i; v[i] = (idx < N) ? cnt[idx] : 0; s += v[i]; }
  sdata[t] = s; __syncthreads();
  int mine = s;
  for(int off=1; off<256; off<<=1){
    int add = (t >= off) ? sdata[t-off] : 0;
    __syncthreads();
    sdata[t] += add;
    __syncthreads();
  }
  int run = sdata[t] - mine + bsum[blockIdx.x];
  #pragma unroll
  for(int i=0;i<4;i++){
    int idx = base+i;
    if(idx < N){
      offs[idx] = run;
      run += v[i];
      if(idx == N-1) offs[N] = run;
    }
  }
}

__global__ void k_fill(const int* __restrict__ rows, const int* __restrict__ cols,
                       const int* __restrict__ offs, int* cursor,
                       int* __restrict__ csr_src, int E, int N){
  int e = blockIdx.x*TPB + threadIdx.x;
  int tot = E + N;
  if(e >= tot) return;
  int r, c;
  if(e < E){ r = rows[e]; c = cols[e]; } else { r = c = e - E; }
  int pos = offs[c] + atomicAdd(&cursor[c], 1);
  csr_src[pos] = r;
}

// ---------------- layer 1 GEMM: xt1 = x @ W1   (N x 256) @ (256 x 128) ----------------
// 128x128 tile / 256 threads / 8x8 register tile / LDS-staged A (transposed) + B,
// register prefetch of next k-chunk. LDA/LDB padded to 132 -> worst 2-way LDS
// aliasing (free on gfx950).

#define LDT 132
__global__ __launch_bounds__(256, 2) void k_gemm1(const float* __restrict__ x,
                                                  const float* __restrict__ W,
                                                  float* __restrict__ xt, int N){
  __shared__ float As[16*LDT];   // As[k][m]
  __shared__ float Bs[16*LDT];   // Bs[k][n]
  const float4* x4 = (const float4*)x;
  const float4* W4 = (const float4*)W;
  int tid = threadIdx.x;
  int n0 = blockIdx.x * 128;

  int ra = tid >> 2, c4 = tid & 3;      // A staging: rows ra, ra+64; k-quad c4
  int kb = tid >> 5, n4 = tid & 31;     // B staging: k rows kb, kb+8; col-quad n4
  int mA = (tid >> 4) * 8;              // compute: 8 rows
  int nB = (tid & 15) * 4;              // compute: cols nB..nB+3, nB+64..nB+67

  float acc[8][8];
  #pragma unroll
  for(int r=0;r<8;r++)
    #pragma unroll
    for(int c=0;c<8;c++) acc[r][c] = 0.f;

  const float4 z4 = make_float4(0.f,0.f,0.f,0.f);
  float4 pa0, pa1, pb0, pb1;
  // prefetch chunk 0
  pa0 = (n0+ra    < N) ? x4[(size_t)(n0+ra   )*64 + c4] : z4;
  pa1 = (n0+ra+64 < N) ? x4[(size_t)(n0+ra+64)*64 + c4] : z4;
  pb0 = W4[(size_t)(kb  )*32 + n4];
  pb1 = W4[(size_t)(kb+8)*32 + n4];

  for(int ch=0; ch<16; ch++){
    // stage regs -> LDS (A transposed)
    As[(c4*4+0)*LDT + ra]      = pa0.x;
    As[(c4*4+1)*LDT + ra]      = pa0.y;
    As[(c4*4+2)*LDT + ra]      = pa0.z;
    As[(c4*4+3)*LDT + ra]      = pa0.w;
    As[(c4*4+0)*LDT + ra+64]   = pa1.x;
    As[(c4*4+1)*LDT + ra+64]   = pa1.y;
    As[(c4*4+2)*LDT + ra+64]   = pa1.z;
    As[(c4*4+3)*LDT + ra+64]   = pa1.w;
    *((float4*)&Bs[(kb  )*LDT + n4*4]) = pb0;
    *((float4*)&Bs[(kb+8)*LDT + n4*4]) = pb1;
    __syncthreads();
    // prefetch next chunk while computing this one
    if(ch < 15){
      pa0 = (n0+ra    < N) ? x4[(size_t)(n0+ra   )*64 + (ch+1)*4 + c4] : z4;
      pa1 = (n0+ra+64 < N) ? x4[(size_t)(n0+ra+64)*64 + (ch+1)*4 + c4] : z4;
      pb0 = W4[(size_t)((ch+1)*16 + kb  )*32 + n4];
      pb1 = W4[(size_t)((ch+1)*16 + kb+8)*32 + n4];
    }
    #pragma unroll
    for(int k=0;k<16;k++){
      float4 a0 = *((const float4*)&As[k*LDT + mA]);
      float4 a1 = *((const float4*)&As[k*LDT + mA + 4]);
      float4 b0 = *((const float4*)&Bs[k*LDT + nB]);
      float4 b1 = *((const float4*)&Bs[k*LDT + nB + 64]);
      float av[8] = {a0.x,a0.y,a0.z,a0.w,a1.x,a1.y,a1.z,a1.w};
      float bv[8] = {b0.x,b0.y,b0.z,b0.w,b1.x,b1.y,b1.z,b1.w};
      #pragma unroll
      for(int r=0;r<8;r++)
        #pragma unroll
        for(int c=0;c<8;c++)
          acc[r][c] += av[r]*bv[c];
    }
    __syncthreads();
  }

  #pragma unroll
  for(int r=0;r<8;r++){
    int row = n0 + mA + r;
    if(row < N){
      *((float4*)&xt[(size_t)row*128 + nB])      = make_float4(acc[r][0],acc[r][1],acc[r][2],acc[r][3]);
      *((float4*)&xt[(size_t)row*128 + nB + 64]) = make_float4(acc[r][4],acc[r][5],acc[r][6],acc[r][7]);
    }
  }
}

// per-node attention scalars, layer 1: s_l[n,h], s_r[n,h]
__global__ void k_sr1(const float* __restrict__ xt, const float* __restrict__ att1,
                      float* __restrict__ sl, float* __restrict__ sr, int N){
  int i = blockIdx.x*TPB + threadIdx.x;   // i = n*4 + h
  if(i >= N*4) return;
  int n = i >> 2, hh = i & 3;
  const float* xp = xt + (size_t)n*128 + hh*32;
  const float* al = att1 + hh*64;
  const float* ar = al + 32;
  float a = 0.f, b = 0.f;
  #pragma unroll
  for(int c=0;c<32;c++){ float v = xp[c]; a += v*al[c]; b += v*ar[c]; }
  sl[i] = a; sr[i] = b;
}

// ---------------- layer 1 aggregation: one wave per target node ----------------
// Per-edge scalar work (alpha, exp) distributed across lanes; 64-edge chunks
// staged through LDS; feature gather uses scalar-base loads (readfirstlane).

__global__ __launch_bounds__(64) void k_agg1(const int* __restrict__ offs, const int* __restrict__ srcs,
    const float* __restrict__ sl, const float* __restrict__ sr, const float* __restrict__ dinv,
    const float* __restrict__ xt, const float* __restrict__ b1, float* __restrict__ h, int N){
  __shared__ int   s_sh[64];
  __shared__ float w_sh[64*4];
  int n = blockIdx.x;
  if(n >= N) return;
  int lane = threadIdx.x;
  int beg = offs[n], end = offs[n+1];
  float4 sln = *((const float4*)(sl + (size_t)n*4));
  // pass 1: per-lane max over its edge subset, then wave reduce
  float m0=-1e30f,m1=-1e30f,m2=-1e30f,m3=-1e30f;
  for(int j=beg+lane; j<end; j+=64){
    int s = srcs[j];
    float4 a = *((const float4*)(sr + (size_t)s*4));
    m0 = fmaxf(m0, lrelu(sln.x + a.x));
    m1 = fmaxf(m1, lrelu(sln.y + a.y));
    m2 = fmaxf(m2, lrelu(sln.z + a.z));
    m3 = fmaxf(m3, lrelu(sln.w + a.w));
  }
  #pragma unroll
  for(int o=32;o>0;o>>=1){
    m0 = fmaxf(m0, __shfl_xor(m0,o));
    m1 = fmaxf(m1, __shfl_xor(m1,o));
    m2 = fmaxf(m2, __shfl_xor(m2,o));
    m3 = fmaxf(m3, __shfl_xor(m3,o));
  }
  int h0 = lane >> 5;           // which head within the pair
  float den0=0.f,den1=0.f,den2=0.f,den3=0.f;
  float acc0=0.f, acc1=0.f;
  for(int c0=beg; c0<end; c0+=64){
    int cnt = min(64, end-c0);
    int j = c0 + lane;
    float e0=0.f,e1=0.f,e2=0.f,e3=0.f, wd=0.f; int s=0;
    if(j<end){
      s = srcs[j];
      float4 a = *((const float4*)(sr + (size_t)s*4));
      e0 = __expf(lrelu(sln.x + a.x) - m0);
      e1 = __expf(lrelu(sln.y + a.y) - m1);
      e2 = __expf(lrelu(sln.z + a.z) - m2);
      e3 = __expf(lrelu(sln.w + a.w) - m3);
      wd = dinv[s];
    }
    den0+=e0; den1+=e1; den2+=e2; den3+=e3;
    s_sh[lane] = s;
    w_sh[lane*4+0] = wd*e0;     // order (e0,e2,e1,e3): lane reads float2 at 4k+2*h0
    w_sh[lane*4+1] = wd*e2;
    w_sh[lane*4+2] = wd*e1;
    w_sh[lane*4+3] = wd*e3;
    __syncthreads();
    for(int k=0;k<cnt;k++){
      int sk = __builtin_amdgcn_readfirstlane(s_sh[k]);
      float2 wv = *((const float2*)&w_sh[k*4 + h0*2]);
      const float* xr = xt + (size_t)sk*128;
      acc0 += wv.x * xr[lane];
      acc1 += wv.y * xr[64+lane];
    }
    __syncthreads();
  }
  #pragma unroll
  for(int o=32;o>0;o>>=1){
    den0 += __shfl_xor(den0,o);
    den1 += __shfl_xor(den1,o);
    den2 += __shfl_xor(den2,o);
    den3 += __shfl_xor(den3,o);
  }
  float din = dinv[n];
  float d0 = (h0==0) ? den0 : den1;
  float d1 = (h0==0) ? den2 : den3;
  float o0 = din*acc0/(d0 + 1e-16f) + b1[lane];
  float o1 = din*acc1/(d1 + 1e-16f) + b1[64+lane];
  h[(size_t)n*128 + lane]      = o0 > 0.f ? o0 : 0.f;   // fused ReLU
  h[(size_t)n*128 + 64 + lane] = o1 > 0.f ? o1 : 0.f;
}

// ---------------- layer 2 GEMM (128->16) + attention scalars fused ----------------

__global__ __launch_bounds__(256) void k_gemm2(const float* __restrict__ hmat, const float* __restrict__ W2,
    const float* __restrict__ att2, float* __restrict__ xt2,
    float* __restrict__ sl2, float* __restrict__ sr2, int N){
  __shared__ float hs[16*132];
  __shared__ float ws[16*132];   // transposed, padded: ws[c*132+k]
  __shared__ float xs[16*16];
  int t = threadIdx.x;
  int n0 = blockIdx.x * 16;
  #pragma unroll
  for(int i=0;i<8;i++){
    int idx = t + 256*i;         // 0..2047
    int k = idx >> 4, c = idx & 15;
    ws[c*132 + k] = W2[idx];
  }
  #pragma unroll
  for(int i=0;i<2;i++){
    int idx = t + 256*i;         // float4 idx 0..511
    int r = idx >> 5, k4 = idx & 31;
    int n = n0 + r;
    float4 v = make_float4(0.f,0.f,0.f,0.f);
    if(n < N) v = ((const float4*)hmat)[(size_t)n*32 + k4];
    *((float4*)&hs[r*132 + k4*4]) = v;
  }
  __syncthreads();
  int r = t >> 4, c = t & 15;
  float acc = 0.f;
  for(int k=0;k<128;k+=4){
    float4 hv = *((const float4*)&hs[r*132+k]);
    float4 wv = *((const float4*)&ws[c*132+k]);
    acc += hv.x*wv.x + hv.y*wv.y + hv.z*wv.z + hv.w*wv.w;
  }
  int n = n0 + r;
  if(n < N) xt2[(size_t)n*16 + c] = acc;
  xs[r*16 + c] = acc;
  __syncthreads();
  if(t < 16){
    int nn = n0 + t;
    if(nn < N){
      float a = 0.f, b = 0.f;
      #pragma unroll
      for(int cc=0;cc<16;cc++){ float v = xs[t*16+cc]; a += v*att2[cc]; b += v*att2[16+cc]; }
      sl2[nn] = a; sr2[nn] = b;
    }
  }
}

// ---------------- layer 2 aggregation ----------------
// 4 edges x 16 channels per iteration; cross-group shuffle reduce.

__global__ __launch_bounds__(64) void k_agg2(const int* __restrict__ offs, const int* __restrict__ srcs,
    const float* __restrict__ sl2, const float* __restrict__ sr2, const float* __restrict__ dinv,
    const float* __restrict__ xt2, const float* __restrict__ b2, float* __restrict__ out, int N){
  __shared__ int   s_sh[64];
  __shared__ float w_sh[64];
  int n = blockIdx.x;
  if(n >= N) return;
  int lane = threadIdx.x;
  int beg = offs[n], end = offs[n+1];
  float sln = sl2[n];
  float m = -1e30f;
  for(int j=beg+lane; j<end; j+=64)
    m = fmaxf(m, lrelu(sln + sr2[srcs[j]]));
  #pragma unroll
  for(int o=32;o>0;o>>=1) m = fmaxf(m, __shfl_xor(m,o));
  float den = 0.f, acc = 0.f;
  int grp = lane >> 4, ch = lane & 15;
  for(int c0=beg; c0<end; c0+=64){
    int cnt = min(64, end-c0);
    int j = c0 + lane;
    float e=0.f, wd=0.f; int s=0;
    if(j<end){
      s = srcs[j];
      e = __expf(lrelu(sln + sr2[s]) - m);
      wd = dinv[s];
    }
    den += e;
    s_sh[lane] = s;
    w_sh[lane] = wd*e;
    __syncthreads();
    for(int k=0;k<cnt;k+=4){
      int kk = k + grp;
      if(kk < cnt){
        int sk = s_sh[kk];
        float wk = w_sh[kk];
        acc += wk * xt2[(size_t)sk*16 + ch];
      }
    }
    __syncthreads();
  }
  #pragma unroll
  for(int o=32;o>0;o>>=1) den += __shfl_xor(den,o);
  acc += __shfl_xor(acc,16);
  acc += __shfl_xor(acc,32);
  if(lane < 16) out[(size_t)n*16 + lane] = dinv[n]*acc/(den + 1e-16f) + b2[lane];
}

// ---------------- host launch ----------------

extern "C" void kernel_launch(void* const* d_in, const int* in_sizes, int n_in,
                              void* d_out, int out_size, void* d_ws, size_t ws_size,
                              hipStream_t stream){
  const float* x    = (const float*)d_in[0];
  const int*   ei   = (const int*)d_in[1];
  const float* W1   = (const float*)d_in[2];
  const float* att1 = (const float*)d_in[3];
  const float* b1   = (const float*)d_in[4];
  const float* W2   = (const float*)d_in[5];
  const float* att2 = (const float*)d_in[6];
  const float* b2   = (const float*)d_in[7];
  int N = in_sizes[0] / 256;
  int E = in_sizes[1] / 2;
  const int* rows = ei;
  const int* cols = ei + E;
  float* out = (float*)d_out;

  char* p = (char*)d_ws;
  auto alloc = [&](size_t bytes)->void*{ void* q = p; p += (bytes + 255) & ~(size_t)255; return q; };
  int*   deg    = (int*)alloc((size_t)N*4);
  int*   cnt    = (int*)alloc((size_t)N*4);
  int*   cursor = (int*)alloc((size_t)N*4);
  int*   offs   = (int*)alloc((size_t)(N+1)*4);
  int*   bsum   = (int*)alloc(256*4);
  int*   csr    = (int*)alloc((size_t)(E+N)*4);
  float* dinv   = (float*)alloc((size_t)N*4);
  float* xt1    = (float*)alloc((size_t)N*128*4);
  float* sl1    = (float*)alloc((size_t)N*16);
  float* sr1    = (float*)alloc((size_t)N*16);
  float* hbuf   = (float*)alloc((size_t)N*128*4);
  float* xt2    = (float*)alloc((size_t)N*16*4);
  float* sl2    = (float*)alloc((size_t)N*4);
  float* sr2    = (float*)alloc((size_t)N*4);

  int gN   = (N + TPB - 1) / TPB;
  int gE   = (E + TPB - 1) / TPB;
  int gEN  = (E + N + TPB - 1) / TPB;
  int NB   = (N + 1023) / 1024;

  k_init<<<gN, TPB, 0, stream>>>(deg, cnt, cursor, N);
  k_count<<<gE, TPB, 0, stream>>>(rows, cols, deg, cnt, E);
  k_dinv<<<gN, TPB, 0, stream>>>(deg, dinv, N);
  k_scan_block<<<NB, 256, 0, stream>>>(cnt, bsum, N);
  k_scan_bsum<<<1, 256, 0, stream>>>(bsum, NB);
  k_scan_write<<<NB, 256, 0, stream>>>(cnt, bsum, offs, N);
  k_fill<<<gEN, TPB, 0, stream>>>(rows, cols, offs, cursor, csr, E, N);

  k_gemm1<<<(N + 127)/128, 256, 0, stream>>>(x, W1, xt1, N);
  k_sr1<<<(4*N + TPB - 1)/TPB, TPB, 0, stream>>>(xt1, att1, sl1, sr1, N);
  k_agg1<<<N, 64, 0, stream>>>(offs, csr, sl1, sr1, dinv, xt1, b1, hbuf, N);

  k_gemm2<<<(N + 15)/16, 256, 0, stream>>>(hbuf, W2, att2, xt2, sl2, sr2, N);
  k_agg2<<<N, 64, 0, stream>>>(offs, csr, sl2, sr2, dinv, xt2, b2, out, N);
}

// Round 4
// 679.716 us; speedup vs baseline: 1.5477x; 1.1252x over previous
//
#include <hip/hip_runtime.h>
#include <math.h>

#define TPB 256

__device__ __forceinline__ float lrelu(float a){ return a >= 0.f ? a : 0.2f*a; }

typedef __attribute__((ext_vector_type(8))) short bf16x8;
typedef __attribute__((ext_vector_type(4))) float f32x4;

// round-to-nearest-even fp32 -> bf16 bits
__device__ __forceinline__ unsigned short bfr(float f){
  unsigned u = __float_as_uint(f);
  return (unsigned short)((u + 0x7fffu + ((u >> 16) & 1u)) >> 16);
}

// ---------------- graph degree / CSR build ----------------

__global__ void k_init(int* deg, int* cnt, int* cursor, int N){
  int i = blockIdx.x*TPB + threadIdx.x;
  if(i < N){ deg[i] = 1; cnt[i] = 1; cursor[i] = 0; }  // 1 = self-loop
}

__global__ void k_count(const int* __restrict__ rows, const int* __restrict__ cols,
                        int* deg, int* cnt, int E){
  int e = blockIdx.x*TPB + threadIdx.x;
  if(e < E){
    atomicAdd(&deg[rows[e]], 1);   // degree over ROW (source) per reference gcn_norm
    atomicAdd(&cnt[cols[e]], 1);   // CSR counts over COL (target)
  }
}

__global__ void k_dinv(const int* __restrict__ deg, float* __restrict__ dinv, int N){
  int i = blockIdx.x*TPB + threadIdx.x;
  if(i < N) dinv[i] = 1.f / sqrtf((float)deg[i]);
}

// exclusive scan of cnt[0..N) into offs[0..N], 1024 elements per block
__global__ void k_scan_block(const int* __restrict__ cnt, int* __restrict__ bsum, int N){
  __shared__ int sdata[256];
  int base = blockIdx.x*1024 + threadIdx.x*4;
  int s = 0;
  #pragma unroll
  for(int i=0;i<4;i++){ int idx = base+i; if(idx < N) s += cnt[idx]; }
  sdata[threadIdx.x] = s; __syncthreads();
  for(int off=128; off>0; off>>=1){
    if(threadIdx.x < off) sdata[threadIdx.x] += sdata[threadIdx.x+off];
    __syncthreads();
  }
  if(threadIdx.x == 0) bsum[blockIdx.x] = sdata[0];
}

__global__ void k_scan_bsum(int* bsum, int NB){
  __shared__ int s[256];
  int t = threadIdx.x;
  int v = (t < NB) ? bsum[t] : 0;
  s[t] = v; __syncthreads();
  for(int off=1; off<256; off<<=1){
    int add = (t >= off) ? s[t-off] : 0;
    __syncthreads();
    s[t] += add;
    __syncthreads();
  }
  if(t < NB) bsum[t] = s[t] - v;   // exclusive
}

__global__ void k_scan_write(const int* __restrict__ cnt, const int* __restrict__ bsum,
                             int* __restrict__ offs, int N){
  __shared__ int sdata[256];
  int t = threadIdx.x;
  int base = blockIdx.x*1024 + t*4;
  int v[4]; int s = 0;
  #pragma unroll
  for(int i=0;i<4;i++){ int idx = base+i; v[i] = (idx < N) ? cnt[idx] : 0; s += v[i]; }
  sdata[t] = s; __syncthreads();
  int mine = s;
  for(int off=1; off<256; off<<=1){
    int add = (t >= off) ? sdata[t-off] : 0;
    __syncthreads();
    sdata[t] += add;
    __syncthreads();
  }
  int run = sdata[t] - mine + bsum[blockIdx.x];
  #pragma unroll
  for(int i=0;i<4;i++){
    int idx = base+i;
    if(idx < N){
      offs[idx] = run;
      run += v[i];
      if(idx == N-1) offs[N] = run;
    }
  }
}

__global__ void k_fill(const int* __restrict__ rows, const int* __restrict__ cols,
                       const int* __restrict__ offs, int* cursor,
                       int* __restrict__ csr_src, int E, int N){
  int e = blockIdx.x*TPB + threadIdx.x;
  int tot = E + N;
  if(e >= tot) return;
  int r, c;
  if(e < E){ r = rows[e]; c = cols[e]; } else { r = c = e - E; }
  int pos = offs[c] + atomicAdd(&cursor[c], 1);
  csr_src[pos] = r;
}

// ---------------- W1 prep: transpose + bf16 hi/lo split ----------------
// Wt_hi[n][k], Wt_lo[n][k]  (n=0..127, k=0..255)

__global__ void k_prepW(const float* __restrict__ W, short* __restrict__ Whi,
                        short* __restrict__ Wlo){
  int idx = blockIdx.x*256 + threadIdx.x;   // 32768
  int n = idx >> 8, k = idx & 255;
  float f = W[k*128 + n];
  unsigned short h = bfr(f);
  float hf = __uint_as_float(((unsigned)h) << 16);
  Whi[n*256 + k] = (short)h;
  Wlo[n*256 + k] = (short)bfr(f - hf);
}

// ---------------- layer 1 GEMM via split-bf16 MFMA ----------------
// xt1 = x @ W1  (100000x256)@(256x128), fp32 in/out.
// A = Ah + Al, B = Bh + Bl (bf16 RNE split); C ~= Ah@Bh + Ah@Bl + Al@Bh.
// 128x128 block tile, 4 waves (2x2 of 64x64), mfma_f32_16x16x32_bf16, BK=32.
// LDS rows padded to 40 shorts -> frag reads <=2-way bank alias (free).

#define SA 40
__global__ __launch_bounds__(256) void k_gemm1(const float* __restrict__ x,
    const short* __restrict__ Whi, const short* __restrict__ Wlo,
    float* __restrict__ xt, int N){
  __shared__ __align__(16) short Ah[128*SA];
  __shared__ __align__(16) short Al[128*SA];
  __shared__ __align__(16) short Bh[128*SA];
  __shared__ __align__(16) short Bl[128*SA];
  const float4* x4 = (const float4*)x;
  int tid = threadIdx.x;
  int n0 = blockIdx.x * 128;
  int w = tid >> 6, l = tid & 63;
  int wm = w & 1, wn = w >> 1;
  int lm = l & 15, lq = l >> 4;

  f32x4 acc[4][4];
  #pragma unroll
  for(int a=0;a<4;a++)
    #pragma unroll
    for(int b=0;b<4;b++) acc[a][b] = (f32x4){0.f,0.f,0.f,0.f};

  for(int c=0;c<8;c++){
    // stage A: x tile 128 rows x 32 k (fp32), convert to bf16 hi/lo
    #pragma unroll
    for(int i=0;i<4;i++){
      int idx = tid + 256*i;            // 0..1023 float4s
      int r = idx >> 3, kq = idx & 7;
      int row = n0 + r;
      float4 v = make_float4(0.f,0.f,0.f,0.f);
      if(row < N) v = x4[(size_t)row*64 + c*8 + kq];
      unsigned short h0=bfr(v.x), h1=bfr(v.y), h2=bfr(v.z), h3=bfr(v.w);
      float l0 = v.x - __uint_as_float(((unsigned)h0)<<16);
      float l1 = v.y - __uint_as_float(((unsigned)h1)<<16);
      float l2 = v.z - __uint_as_float(((unsigned)h2)<<16);
      float l3 = v.w - __uint_as_float(((unsigned)h3)<<16);
      unsigned hi01 = (unsigned)h0 | ((unsigned)h1<<16);
      unsigned hi23 = (unsigned)h2 | ((unsigned)h3<<16);
      unsigned lo01 = (unsigned)bfr(l0) | ((unsigned)bfr(l1)<<16);
      unsigned lo23 = (unsigned)bfr(l2) | ((unsigned)bfr(l3)<<16);
      *((uint2*)&Ah[r*SA + kq*4]) = make_uint2(hi01, hi23);
      *((uint2*)&Al[r*SA + kq*4]) = make_uint2(lo01, lo23);
    }
    // stage B: pre-split Wt rows (bf16), 128 rows x 32 k
    #pragma unroll
    for(int i=0;i<2;i++){
      int idx = tid + 256*i;            // 0..511 x (16B)
      int r = idx >> 2, q = idx & 3;
      *((uint4*)&Bh[r*SA + q*8]) = *((const uint4*)(Whi + r*256 + c*32 + q*8));
      *((uint4*)&Bl[r*SA + q*8]) = *((const uint4*)(Wlo + r*256 + c*32 + q*8));
    }
    __syncthreads();
    bf16x8 ah[4], al[4];
    #pragma unroll
    for(int mt=0;mt<4;mt++){
      int rr = wm*64 + mt*16 + lm;
      ah[mt] = *((bf16x8*)&Ah[rr*SA + lq*8]);
      al[mt] = *((bf16x8*)&Al[rr*SA + lq*8]);
    }
    #pragma unroll
    for(int nt=0;nt<4;nt++){
      int rr = wn*64 + nt*16 + lm;
      bf16x8 bh = *((bf16x8*)&Bh[rr*SA + lq*8]);
      bf16x8 bl = *((bf16x8*)&Bl[rr*SA + lq*8]);
      #pragma unroll
      for(int mt=0;mt<4;mt++){
        acc[mt][nt] = __builtin_amdgcn_mfma_f32_16x16x32_bf16(ah[mt], bh, acc[mt][nt], 0,0,0);
        acc[mt][nt] = __builtin_amdgcn_mfma_f32_16x16x32_bf16(ah[mt], bl, acc[mt][nt], 0,0,0);
        acc[mt][nt] = __builtin_amdgcn_mfma_f32_16x16x32_bf16(al[mt], bh, acc[mt][nt], 0,0,0);
      }
    }
    __syncthreads();
  }
  // epilogue: C/D layout col=lane&15, row=lq*4+reg  [verified m89]
  #pragma unroll
  for(int mt=0;mt<4;mt++){
    #pragma unroll
    for(int v=0;v<4;v++){
      int row = n0 + wm*64 + mt*16 + lq*4 + v;
      if(row < N){
        #pragma unroll
        for(int nt=0;nt<4;nt++)
          xt[(size_t)row*128 + wn*64 + nt*16 + lm] = acc[mt][nt][v];
      }
    }
  }
}

// per-node attention scalars, layer 1: s_l[n,h], s_r[n,h]
__global__ void k_sr1(const float* __restrict__ xt, const float* __restrict__ att1,
                      float* __restrict__ sl, float* __restrict__ sr, int N){
  int i = blockIdx.x*TPB + threadIdx.x;   // i = n*4 + h
  if(i >= N*4) return;
  int n = i >> 2, hh = i & 3;
  const float* xp = xt + (size_t)n*128 + hh*32;
  const float* al = att1 + hh*64;
  const float* ar = al + 32;
  float a = 0.f, b = 0.f;
  #pragma unroll
  for(int c=0;c<32;c++){ float v = xp[c]; a += v*al[c]; b += v*ar[c]; }
  sl[i] = a; sr[i] = b;
}

// ---------------- layer 1 aggregation: one wave per target node ----------------

__global__ __launch_bounds__(64) void k_agg1(const int* __restrict__ offs, const int* __restrict__ srcs,
    const float* __restrict__ sl, const float* __restrict__ sr, const float* __restrict__ dinv,
    const float* __restrict__ xt, const float* __restrict__ b1, float* __restrict__ h, int N){
  __shared__ int   s_sh[64];
  __shared__ float w_sh[64*4];
  int n = blockIdx.x;
  if(n >= N) return;
  int lane = threadIdx.x;
  int beg = offs[n], end = offs[n+1];
  float4 sln = *((const float4*)(sl + (size_t)n*4));
  float m0=-1e30f,m1=-1e30f,m2=-1e30f,m3=-1e30f;
  for(int j=beg+lane; j<end; j+=64){
    int s = srcs[j];
    float4 a = *((const float4*)(sr + (size_t)s*4));
    m0 = fmaxf(m0, lrelu(sln.x + a.x));
    m1 = fmaxf(m1, lrelu(sln.y + a.y));
    m2 = fmaxf(m2, lrelu(sln.z + a.z));
    m3 = fmaxf(m3, lrelu(sln.w + a.w));
  }
  #pragma unroll
  for(int o=32;o>0;o>>=1){
    m0 = fmaxf(m0, __shfl_xor(m0,o));
    m1 = fmaxf(m1, __shfl_xor(m1,o));
    m2 = fmaxf(m2, __shfl_xor(m2,o));
    m3 = fmaxf(m3, __shfl_xor(m3,o));
  }
  int h0 = lane >> 5;
  float den0=0.f,den1=0.f,den2=0.f,den3=0.f;
  float acc0=0.f, acc1=0.f;
  for(int c0=beg; c0<end; c0+=64){
    int cnt = min(64, end-c0);
    int j = c0 + lane;
    float e0=0.f,e1=0.f,e2=0.f,e3=0.f, wd=0.f; int s=0;
    if(j<end){
      s = srcs[j];
      float4 a = *((const float4*)(sr + (size_t)s*4));
      e0 = __expf(lrelu(sln.x + a.x) - m0);
      e1 = __expf(lrelu(sln.y + a.y) - m1);
      e2 = __expf(lrelu(sln.z + a.z) - m2);
      e3 = __expf(lrelu(sln.w + a.w) - m3);
      wd = dinv[s];
    }
    den0+=e0; den1+=e1; den2+=e2; den3+=e3;
    s_sh[lane] = s;
    w_sh[lane*4+0] = wd*e0;
    w_sh[lane*4+1] = wd*e2;
    w_sh[lane*4+2] = wd*e1;
    w_sh[lane*4+3] = wd*e3;
    __syncthreads();
    for(int k=0;k<cnt;k++){
      int sk = __builtin_amdgcn_readfirstlane(s_sh[k]);
      float2 wv = *((const float2*)&w_sh[k*4 + h0*2]);
      const float* xr = xt + (size_t)sk*128;
      acc0 += wv.x * xr[lane];
      acc1 += wv.y * xr[64+lane];
    }
    __syncthreads();
  }
  #pragma unroll
  for(int o=32;o>0;o>>=1){
    den0 += __shfl_xor(den0,o);
    den1 += __shfl_xor(den1,o);
    den2 += __shfl_xor(den2,o);
    den3 += __shfl_xor(den3,o);
  }
  float din = dinv[n];
  float d0 = (h0==0) ? den0 : den1;
  float d1 = (h0==0) ? den2 : den3;
  float o0 = din*acc0/(d0 + 1e-16f) + b1[lane];
  float o1 = din*acc1/(d1 + 1e-16f) + b1[64+lane];
  h[(size_t)n*128 + lane]      = o0 > 0.f ? o0 : 0.f;
  h[(size_t)n*128 + 64 + lane] = o1 > 0.f ? o1 : 0.f;
}

// ---------------- layer 2 GEMM (128->16) + attention scalars fused ----------------

__global__ __launch_bounds__(256) void k_gemm2(const float* __restrict__ hmat, const float* __restrict__ W2,
    const float* __restrict__ att2, float* __restrict__ xt2,
    float* __restrict__ sl2, float* __restrict__ sr2, int N){
  __shared__ float hs[16*132];
  __shared__ float ws[16*132];
  __shared__ float xs[16*16];
  int t = threadIdx.x;
  int n0 = blockIdx.x * 16;
  #pragma unroll
  for(int i=0;i<8;i++){
    int idx = t + 256*i;
    int k = idx >> 4, c = idx & 15;
    ws[c*132 + k] = W2[idx];
  }
  #pragma unroll
  for(int i=0;i<2;i++){
    int idx = t + 256*i;
    int r = idx >> 5, k4 = idx & 31;
    int n = n0 + r;
    float4 v = make_float4(0.f,0.f,0.f,0.f);
    if(n < N) v = ((const float4*)hmat)[(size_t)n*32 + k4];
    *((float4*)&hs[r*132 + k4*4]) = v;
  }
  __syncthreads();
  int r = t >> 4, c = t & 15;
  float acc = 0.f;
  for(int k=0;k<128;k+=4){
    float4 hv = *((const float4*)&hs[r*132+k]);
    float4 wv = *((const float4*)&ws[c*132+k]);
    acc += hv.x*wv.x + hv.y*wv.y + hv.z*wv.z + hv.w*wv.w;
  }
  int n = n0 + r;
  if(n < N) xt2[(size_t)n*16 + c] = acc;
  xs[r*16 + c] = acc;
  __syncthreads();
  if(t < 16){
    int nn = n0 + t;
    if(nn < N){
      float a = 0.f, b = 0.f;
      #pragma unroll
      for(int cc=0;cc<16;cc++){ float v = xs[t*16+cc]; a += v*att2[cc]; b += v*att2[16+cc]; }
      sl2[nn] = a; sr2[nn] = b;
    }
  }
}

// ---------------- layer 2 aggregation ----------------

__global__ __launch_bounds__(64) void k_agg2(const int* __restrict__ offs, const int* __restrict__ srcs,
    const float* __restrict__ sl2, const float* __restrict__ sr2, const float* __restrict__ dinv,
    const float* __restrict__ xt2, const float* __restrict__ b2, float* __restrict__ out, int N){
  __shared__ int   s_sh[64];
  __shared__ float w_sh[64];
  int n = blockIdx.x;
  if(n >= N) return;
  int lane = threadIdx.x;
  int beg = offs[n], end = offs[n+1];
  float sln = sl2[n];
  float m = -1e30f;
  for(int j=beg+lane; j<end; j+=64)
    m = fmaxf(m, lrelu(sln + sr2[srcs[j]]));
  #pragma unroll
  for(int o=32;o>0;o>>=1) m = fmaxf(m, __shfl_xor(m,o));
  float den = 0.f, acc = 0.f;
  int grp = lane >> 4, ch = lane & 15;
  for(int c0=beg; c0<end; c0+=64){
    int cnt = min(64, end-c0);
    int j = c0 + lane;
    float e=0.f, wd=0.f; int s=0;
    if(j<end){
      s = srcs[j];
      e = __expf(lrelu(sln + sr2[s]) - m);
      wd = dinv[s];
    }
    den += e;
    s_sh[lane] = s;
    w_sh[lane] = wd*e;
    __syncthreads();
    for(int k=0;k<cnt;k+=4){
      int kk = k + grp;
      if(kk < cnt){
        int sk = s_sh[kk];
        float wk = w_sh[kk];
        acc += wk * xt2[(size_t)sk*16 + ch];
      }
    }
    __syncthreads();
  }
  #pragma unroll
  for(int o=32;o>0;o>>=1) den += __shfl_xor(den,o);
  acc += __shfl_xor(acc,16);
  acc += __shfl_xor(acc,32);
  if(lane < 16) out[(size_t)n*16 + lane] = dinv[n]*acc/(den + 1e-16f) + b2[lane];
}

// ---------------- host launch ----------------

extern "C" void kernel_launch(void* const* d_in, const int* in_sizes, int n_in,
                              void* d_out, int out_size, void* d_ws, size_t ws_size,
                              hipStream_t stream){
  const float* x    = (const float*)d_in[0];
  const int*   ei   = (const int*)d_in[1];
  const float* W1   = (const float*)d_in[2];
  const float* att1 = (const float*)d_in[3];
  const float* b1   = (const float*)d_in[4];
  const float* W2   = (const float*)d_in[5];
  const float* att2 = (const float*)d_in[6];
  const float* b2   = (const float*)d_in[7];
  int N = in_sizes[0] / 256;
  int E = in_sizes[1] / 2;
  const int* rows = ei;
  const int* cols = ei + E;
  float* out = (float*)d_out;

  char* p = (char*)d_ws;
  auto alloc = [&](size_t bytes)->void*{ void* q = p; p += (bytes + 255) & ~(size_t)255; return q; };
  int*   deg    = (int*)alloc((size_t)N*4);
  int*   cnt    = (int*)alloc((size_t)N*4);
  int*   cursor = (int*)alloc((size_t)N*4);
  int*   offs   = (int*)alloc((size_t)(N+1)*4);
  int*   bsum   = (int*)alloc(256*4);
  int*   csr    = (int*)alloc((size_t)(E+N)*4);
  float* dinv   = (float*)alloc((size_t)N*4);
  float* xt1    = (float*)alloc((size_t)N*128*4);
  float* sl1    = (float*)alloc((size_t)N*16);
  float* sr1    = (float*)alloc((size_t)N*16);
  float* hbuf   = (float*)alloc((size_t)N*128*4);
  float* xt2    = (float*)alloc((size_t)N*16*4);
  float* sl2    = (float*)alloc((size_t)N*4);
  float* sr2    = (float*)alloc((size_t)N*4);
  short* Whi    = (short*)alloc((size_t)128*256*2);
  short* Wlo    = (short*)alloc((size_t)128*256*2);

  int gN   = (N + TPB - 1) / TPB;
  int gE   = (E + TPB - 1) / TPB;
  int gEN  = (E + N + TPB - 1) / TPB;
  int NB   = (N + 1023) / 1024;

  k_init<<<gN, TPB, 0, stream>>>(deg, cnt, cursor, N);
  k_count<<<gE, TPB, 0, stream>>>(rows, cols, deg, cnt, E);
  k_dinv<<<gN, TPB, 0, stream>>>(deg, dinv, N);
  k_scan_block<<<NB, 256, 0, stream>>>(cnt, bsum, N);
  k_scan_bsum<<<1, 256, 0, stream>>>(bsum, NB);
  k_scan_write<<<NB, 256, 0, stream>>>(cnt, bsum, offs, N);
  k_fill<<<gEN, TPB, 0, stream>>>(rows, cols, offs, cursor, csr, E, N);

  k_prepW<<<128, 256, 0, stream>>>(W1, Whi, Wlo);
  k_gemm1<<<(N + 127)/128, 256, 0, stream>>>(x, Whi, Wlo, xt1, N);
  k_sr1<<<(4*N + TPB - 1)/TPB, TPB, 0, stream>>>(xt1, att1, sl1, sr1, N);
  k_agg1<<<N, 64, 0, stream>>>(offs, csr, sl1, sr1, dinv, xt1, b1, hbuf, N);

  k_gemm2<<<(N + 15)/16, 256, 0, stream>>>(hbuf, W2, att2, xt2, sl2, sr2, N);
  k_agg2<<<N, 64, 0, stream>>>(offs, csr, sl2, sr2, dinv, xt2, b2, out, N);
}

// Round 5
// 631.823 us; speedup vs baseline: 1.6650x; 1.0758x over previous
//
#include <hip/hip_runtime.h>
#include <math.h>

#define TPB 256

__device__ __forceinline__ float lrelu(float a){ return a >= 0.f ? a : 0.2f*a; }

typedef __attribute__((ext_vector_type(8))) short bf16x8;
typedef __attribute__((ext_vector_type(4))) float f32x4;

// round-to-nearest-even fp32 -> bf16 bits
__device__ __forceinline__ unsigned short bfr(float f){
  unsigned u = __float_as_uint(f);
  return (unsigned short)((u + 0x7fffu + ((u >> 16) & 1u)) >> 16);
}

// ---------------- graph degree / CSR build ----------------

__global__ void k_init(int* deg, int* cnt, int* cursor, int N){
  int i = blockIdx.x*TPB + threadIdx.x;
  if(i < N){ deg[i] = 1; cnt[i] = 1; cursor[i] = 0; }  // 1 = self-loop
}

__global__ void k_count(const int* __restrict__ rows, const int* __restrict__ cols,
                        int* deg, int* cnt, int E){
  int e = blockIdx.x*TPB + threadIdx.x;
  if(e < E){
    atomicAdd(&deg[rows[e]], 1);   // degree over ROW (source) per reference gcn_norm
    atomicAdd(&cnt[cols[e]], 1);   // CSR counts over COL (target)
  }
}

__global__ void k_dinv(const int* __restrict__ deg, float* __restrict__ dinv, int N){
  int i = blockIdx.x*TPB + threadIdx.x;
  if(i < N) dinv[i] = 1.f / sqrtf((float)deg[i]);
}

// exclusive scan of cnt[0..N) into offs[0..N], 1024 elements per block
__global__ void k_scan_block(const int* __restrict__ cnt, int* __restrict__ bsum, int N){
  __shared__ int sdata[256];
  int base = blockIdx.x*1024 + threadIdx.x*4;
  int s = 0;
  #pragma unroll
  for(int i=0;i<4;i++){ int idx = base+i; if(idx < N) s += cnt[idx]; }
  sdata[threadIdx.x] = s; __syncthreads();
  for(int off=128; off>0; off>>=1){
    if(threadIdx.x < off) sdata[threadIdx.x] += sdata[threadIdx.x+off];
    __syncthreads();
  }
  if(threadIdx.x == 0) bsum[blockIdx.x] = sdata[0];
}

__global__ void k_scan_bsum(int* bsum, int NB){
  __shared__ int s[256];
  int t = threadIdx.x;
  int v = (t < NB) ? bsum[t] : 0;
  s[t] = v; __syncthreads();
  for(int off=1; off<256; off<<=1){
    int add = (t >= off) ? s[t-off] : 0;
    __syncthreads();
    s[t] += add;
    __syncthreads();
  }
  if(t < NB) bsum[t] = s[t] - v;   // exclusive
}

__global__ void k_scan_write(const int* __restrict__ cnt, const int* __restrict__ bsum,
                             int* __restrict__ offs, int N){
  __shared__ int sdata[256];
  int t = threadIdx.x;
  int base = blockIdx.x*1024 + t*4;
  int v[4]; int s = 0;
  #pragma unroll
  for(int i=0;i<4;i++){ int idx = base+i; v[i] = (idx < N) ? cnt[idx] : 0; s += v[i]; }
  sdata[t] = s; __syncthreads();
  int mine = s;
  for(int off=1; off<256; off<<=1){
    int add = (t >= off) ? sdata[t-off] : 0;
    __syncthreads();
    sdata[t] += add;
    __syncthreads();
  }
  int run = sdata[t] - mine + bsum[blockIdx.x];
  #pragma unroll
  for(int i=0;i<4;i++){
    int idx = base+i;
    if(idx < N){
      offs[idx] = run;
      run += v[i];
      if(idx == N-1) offs[N] = run;
    }
  }
}

__global__ void k_fill(const int* __restrict__ rows, const int* __restrict__ cols,
                       const int* __restrict__ offs, int* cursor,
                       int* __restrict__ csr_src, int E, int N){
  int e = blockIdx.x*TPB + threadIdx.x;
  int tot = E + N;
  if(e >= tot) return;
  int r, c;
  if(e < E){ r = rows[e]; c = cols[e]; } else { r = c = e - E; }
  int pos = offs[c] + atomicAdd(&cursor[c], 1);
  csr_src[pos] = r;
}

// ---------------- W1 prep: transpose + bf16 hi/lo split ----------------

__global__ void k_prepW(const float* __restrict__ W, short* __restrict__ Whi,
                        short* __restrict__ Wlo){
  int idx = blockIdx.x*256 + threadIdx.x;   // 32768
  int n = idx >> 8, k = idx & 255;
  float f = W[k*128 + n];
  unsigned short h = bfr(f);
  float hf = __uint_as_float(((unsigned)h) << 16);
  Whi[n*256 + k] = (short)h;
  Wlo[n*256 + k] = (short)bfr(f - hf);
}

// ---------------- layer 1 GEMM via split-bf16 MFMA ----------------
// xt1 = x @ W1. Also emits xtb: bf16 channel pairs (c, c+32) packed per dword
// (gather payload for k_agg1), straight from accumulator registers.

#define SA 40
__global__ __launch_bounds__(256) void k_gemm1(const float* __restrict__ x,
    const short* __restrict__ Whi, const short* __restrict__ Wlo,
    float* __restrict__ xt, unsigned* __restrict__ xtb, int N){
  __shared__ __align__(16) short Ah[128*SA];
  __shared__ __align__(16) short Al[128*SA];
  __shared__ __align__(16) short Bh[128*SA];
  __shared__ __align__(16) short Bl[128*SA];
  const float4* x4 = (const float4*)x;
  int tid = threadIdx.x;
  int n0 = blockIdx.x * 128;
  int w = tid >> 6, l = tid & 63;
  int wm = w & 1, wn = w >> 1;
  int lm = l & 15, lq = l >> 4;

  f32x4 acc[4][4];
  #pragma unroll
  for(int a=0;a<4;a++)
    #pragma unroll
    for(int b=0;b<4;b++) acc[a][b] = (f32x4){0.f,0.f,0.f,0.f};

  for(int c=0;c<8;c++){
    #pragma unroll
    for(int i=0;i<4;i++){
      int idx = tid + 256*i;
      int r = idx >> 3, kq = idx & 7;
      int row = n0 + r;
      float4 v = make_float4(0.f,0.f,0.f,0.f);
      if(row < N) v = x4[(size_t)row*64 + c*8 + kq];
      unsigned short h0=bfr(v.x), h1=bfr(v.y), h2=bfr(v.z), h3=bfr(v.w);
      float l0 = v.x - __uint_as_float(((unsigned)h0)<<16);
      float l1 = v.y - __uint_as_float(((unsigned)h1)<<16);
      float l2 = v.z - __uint_as_float(((unsigned)h2)<<16);
      float l3 = v.w - __uint_as_float(((unsigned)h3)<<16);
      unsigned hi01 = (unsigned)h0 | ((unsigned)h1<<16);
      unsigned hi23 = (unsigned)h2 | ((unsigned)h3<<16);
      unsigned lo01 = (unsigned)bfr(l0) | ((unsigned)bfr(l1)<<16);
      unsigned lo23 = (unsigned)bfr(l2) | ((unsigned)bfr(l3)<<16);
      *((uint2*)&Ah[r*SA + kq*4]) = make_uint2(hi01, hi23);
      *((uint2*)&Al[r*SA + kq*4]) = make_uint2(lo01, lo23);
    }
    #pragma unroll
    for(int i=0;i<2;i++){
      int idx = tid + 256*i;
      int r = idx >> 2, q = idx & 3;
      *((uint4*)&Bh[r*SA + q*8]) = *((const uint4*)(Whi + r*256 + c*32 + q*8));
      *((uint4*)&Bl[r*SA + q*8]) = *((const uint4*)(Wlo + r*256 + c*32 + q*8));
    }
    __syncthreads();
    bf16x8 ah[4], al[4];
    #pragma unroll
    for(int mt=0;mt<4;mt++){
      int rr = wm*64 + mt*16 + lm;
      ah[mt] = *((bf16x8*)&Ah[rr*SA + lq*8]);
      al[mt] = *((bf16x8*)&Al[rr*SA + lq*8]);
    }
    #pragma unroll
    for(int nt=0;nt<4;nt++){
      int rr = wn*64 + nt*16 + lm;
      bf16x8 bh = *((bf16x8*)&Bh[rr*SA + lq*8]);
      bf16x8 bl = *((bf16x8*)&Bl[rr*SA + lq*8]);
      #pragma unroll
      for(int mt=0;mt<4;mt++){
        acc[mt][nt] = __builtin_amdgcn_mfma_f32_16x16x32_bf16(ah[mt], bh, acc[mt][nt], 0,0,0);
        acc[mt][nt] = __builtin_amdgcn_mfma_f32_16x16x32_bf16(ah[mt], bl, acc[mt][nt], 0,0,0);
        acc[mt][nt] = __builtin_amdgcn_mfma_f32_16x16x32_bf16(al[mt], bh, acc[mt][nt], 0,0,0);
      }
    }
    __syncthreads();
  }
  // epilogue: C/D layout col=lane&15, row=lq*4+reg.
  // packed pairs: cols (c, c+32) live in (nt, nt+2) of the same thread.
  #pragma unroll
  for(int mt=0;mt<4;mt++){
    #pragma unroll
    for(int v=0;v<4;v++){
      int row = n0 + wm*64 + mt*16 + lq*4 + v;
      if(row < N){
        #pragma unroll
        for(int nt=0;nt<4;nt++)
          xt[(size_t)row*128 + wn*64 + nt*16 + lm] = acc[mt][nt][v];
        unsigned p0 = (unsigned)bfr(acc[mt][0][v]) | ((unsigned)bfr(acc[mt][2][v])<<16);
        unsigned p1 = (unsigned)bfr(acc[mt][1][v]) | ((unsigned)bfr(acc[mt][3][v])<<16);
        int jb = wn*32 + lm;
        xtb[(size_t)row*64 + jb]      = p0;
        xtb[(size_t)row*64 + jb + 16] = p1;
      }
    }
  }
}

// per-node attention scalars, layer 1: s_l[n,h], s_r[n,h]
__global__ void k_sr1(const float* __restrict__ xt, const float* __restrict__ att1,
                      float* __restrict__ sl, float* __restrict__ sr, int N){
  int i = blockIdx.x*TPB + threadIdx.x;   // i = n*4 + h
  if(i >= N*4) return;
  int n = i >> 2, hh = i & 3;
  const float* xp = xt + (size_t)n*128 + hh*32;
  const float* al = att1 + hh*64;
  const float* ar = al + 32;
  float a = 0.f, b = 0.f;
  #pragma unroll
  for(int c=0;c<32;c++){ float v = xp[c]; a += v*al[c]; b += v*ar[c]; }
  sl[i] = a; sr[i] = b;
}

// ---------------- layer 1 aggregation: one wave per target node ----------------
// bf16-pair payload (1 dword/lane/edge), 8-deep unrolled gather for MLP.

__global__ __launch_bounds__(64) void k_agg1(const int* __restrict__ offs, const int* __restrict__ srcs,
    const float* __restrict__ sl, const float* __restrict__ sr, const float* __restrict__ dinv,
    const unsigned* __restrict__ xtb, const float* __restrict__ b1, float* __restrict__ h, int N){
  __shared__ int   s_sh[64];
  __shared__ float w_sh[64*4];
  int n = blockIdx.x;
  if(n >= N) return;
  int lane = threadIdx.x;
  int beg = offs[n], end = offs[n+1];
  float4 sln = *((const float4*)(sl + (size_t)n*4));
  float m0=-1e30f,m1=-1e30f,m2=-1e30f,m3=-1e30f;
  for(int j=beg+lane; j<end; j+=64){
    int s = srcs[j];
    float4 a = *((const float4*)(sr + (size_t)s*4));
    m0 = fmaxf(m0, lrelu(sln.x + a.x));
    m1 = fmaxf(m1, lrelu(sln.y + a.y));
    m2 = fmaxf(m2, lrelu(sln.z + a.z));
    m3 = fmaxf(m3, lrelu(sln.w + a.w));
  }
  #pragma unroll
  for(int o=32;o>0;o>>=1){
    m0 = fmaxf(m0, __shfl_xor(m0,o));
    m1 = fmaxf(m1, __shfl_xor(m1,o));
    m2 = fmaxf(m2, __shfl_xor(m2,o));
    m3 = fmaxf(m3, __shfl_xor(m3,o));
  }
  int h0 = lane >> 5;
  float den0=0.f,den1=0.f,den2=0.f,den3=0.f;
  float acc0=0.f, acc1=0.f;
  for(int c0=beg; c0<end; c0+=64){
    int cnt = min(64, end-c0);
    int j = c0 + lane;
    float e0=0.f,e1=0.f,e2=0.f,e3=0.f, wd=0.f; int s=0;
    if(j<end){
      s = srcs[j];
      float4 a = *((const float4*)(sr + (size_t)s*4));
      e0 = __expf(lrelu(sln.x + a.x) - m0);
      e1 = __expf(lrelu(sln.y + a.y) - m1);
      e2 = __expf(lrelu(sln.z + a.z) - m2);
      e3 = __expf(lrelu(sln.w + a.w) - m3);
      wd = dinv[s];
    }
    den0+=e0; den1+=e1; den2+=e2; den3+=e3;
    s_sh[lane] = s;
    w_sh[lane*4+0] = wd*e0;
    w_sh[lane*4+1] = wd*e1;
    w_sh[lane*4+2] = wd*e2;
    w_sh[lane*4+3] = wd*e3;
    __syncthreads();
    int k = 0;
    for(; k+8<=cnt; k+=8){
      int sk[8];
      #pragma unroll
      for(int u=0;u<8;u++) sk[u] = __builtin_amdgcn_readfirstlane(s_sh[k+u]);
      unsigned pv[8];
      #pragma unroll
      for(int u=0;u<8;u++) pv[u] = xtb[(size_t)sk[u]*64 + lane];
      #pragma unroll
      for(int u=0;u<8;u++){
        float2 wv = *((const float2*)&w_sh[(k+u)*4 + h0*2]);
        acc0 += wv.x * __uint_as_float(pv[u] << 16);
        acc1 += wv.y * __uint_as_float(pv[u] & 0xffff0000u);
      }
    }
    for(; k<cnt; k++){
      int sk = __builtin_amdgcn_readfirstlane(s_sh[k]);
      unsigned pvv = xtb[(size_t)sk*64 + lane];
      float2 wv = *((const float2*)&w_sh[k*4 + h0*2]);
      acc0 += wv.x * __uint_as_float(pvv << 16);
      acc1 += wv.y * __uint_as_float(pvv & 0xffff0000u);
    }
    __syncthreads();
  }
  #pragma unroll
  for(int o=32;o>0;o>>=1){
    den0 += __shfl_xor(den0,o);
    den1 += __shfl_xor(den1,o);
    den2 += __shfl_xor(den2,o);
    den3 += __shfl_xor(den3,o);
  }
  float din = dinv[n];
  int ch0 = (lane < 32) ? lane : lane + 32;   // pairs (c, c+32)
  int ch1 = ch0 + 32;
  float d0 = (lane < 32) ? den0 : den2;
  float d1 = (lane < 32) ? den1 : den3;
  float o0 = din*acc0/(d0 + 1e-16f) + b1[ch0];
  float o1 = din*acc1/(d1 + 1e-16f) + b1[ch1];
  h[(size_t)n*128 + ch0] = o0 > 0.f ? o0 : 0.f;
  h[(size_t)n*128 + ch1] = o1 > 0.f ? o1 : 0.f;
}

// ---------------- layer 2 GEMM (128->16) + attention scalars, bf16-pair payload ----------------

__global__ __launch_bounds__(256) void k_gemm2(const float* __restrict__ hmat, const float* __restrict__ W2,
    const float* __restrict__ att2, unsigned* __restrict__ xt2b,
    float* __restrict__ sl2, float* __restrict__ sr2, int N){
  __shared__ float hs[16*132];
  __shared__ float ws[16*132];
  __shared__ float xs[16*16];
  int t = threadIdx.x;
  int n0 = blockIdx.x * 16;
  #pragma unroll
  for(int i=0;i<8;i++){
    int idx = t + 256*i;
    int k = idx >> 4, c = idx & 15;
    ws[c*132 + k] = W2[idx];
  }
  #pragma unroll
  for(int i=0;i<2;i++){
    int idx = t + 256*i;
    int r = idx >> 5, k4 = idx & 31;
    int n = n0 + r;
    float4 v = make_float4(0.f,0.f,0.f,0.f);
    if(n < N) v = ((const float4*)hmat)[(size_t)n*32 + k4];
    *((float4*)&hs[r*132 + k4*4]) = v;
  }
  __syncthreads();
  int r = t >> 4, c = t & 15;
  float acc = 0.f;
  for(int k=0;k<128;k+=4){
    float4 hv = *((const float4*)&hs[r*132+k]);
    float4 wv = *((const float4*)&ws[c*132+k]);
    acc += hv.x*wv.x + hv.y*wv.y + hv.z*wv.z + hv.w*wv.w;
  }
  xs[r*16 + c] = acc;
  __syncthreads();
  int n = n0 + r;
  if(c < 8 && n < N){
    unsigned pk = (unsigned)bfr(xs[r*16+c]) | ((unsigned)bfr(xs[r*16+c+8])<<16);
    xt2b[(size_t)n*8 + c] = pk;
  }
  if(t < 16){
    int nn = n0 + t;
    if(nn < N){
      float a = 0.f, b = 0.f;
      #pragma unroll
      for(int cc=0;cc<16;cc++){ float v = xs[t*16+cc]; a += v*att2[cc]; b += v*att2[16+cc]; }
      sl2[nn] = a; sr2[nn] = b;
    }
  }
}

// ---------------- layer 2 aggregation: 8 edge-groups x 8 channel-lanes ----------------

__global__ __launch_bounds__(64) void k_agg2(const int* __restrict__ offs, const int* __restrict__ srcs,
    const float* __restrict__ sl2, const float* __restrict__ sr2, const float* __restrict__ dinv,
    const unsigned* __restrict__ xt2b, const float* __restrict__ b2, float* __restrict__ out, int N){
  __shared__ int   s_sh[64];
  __shared__ float w_sh[64];
  int n = blockIdx.x;
  if(n >= N) return;
  int lane = threadIdx.x;
  int beg = offs[n], end = offs[n+1];
  float sln = sl2[n];
  float m = -1e30f;
  for(int j=beg+lane; j<end; j+=64)
    m = fmaxf(m, lrelu(sln + sr2[srcs[j]]));
  #pragma unroll
  for(int o=32;o>0;o>>=1) m = fmaxf(m, __shfl_xor(m,o));
  float den = 0.f, acc0 = 0.f, acc1 = 0.f;
  int grp = lane >> 3, ch = lane & 7;
  for(int c0=beg; c0<end; c0+=64){
    int cnt = min(64, end-c0);
    int j = c0 + lane;
    float e=0.f, wd=0.f; int s=0;
    if(j<end){
      s = srcs[j];
      e = __expf(lrelu(sln + sr2[s]) - m);
      wd = dinv[s];
    }
    den += e;
    s_sh[lane] = s;
    w_sh[lane] = wd*e;
    __syncthreads();
    for(int k=0;k<cnt;k+=8){
      int kk = k + grp;
      if(kk < cnt){
        int sk = s_sh[kk];
        float wk = w_sh[kk];
        unsigned pv = xt2b[(size_t)sk*8 + ch];
        acc0 += wk * __uint_as_float(pv << 16);
        acc1 += wk * __uint_as_float(pv & 0xffff0000u);
      }
    }
    __syncthreads();
  }
  #pragma unroll
  for(int o=32;o>0;o>>=1) den += __shfl_xor(den,o);
  acc0 += __shfl_xor(acc0,8);  acc0 += __shfl_xor(acc0,16);  acc0 += __shfl_xor(acc0,32);
  acc1 += __shfl_xor(acc1,8);  acc1 += __shfl_xor(acc1,16);  acc1 += __shfl_xor(acc1,32);
  if(lane < 8){
    float din = dinv[n];
    out[(size_t)n*16 + lane]     = din*acc0/(den + 1e-16f) + b2[lane];
    out[(size_t)n*16 + lane + 8] = din*acc1/(den + 1e-16f) + b2[lane+8];
  }
}

// ---------------- host launch ----------------

extern "C" void kernel_launch(void* const* d_in, const int* in_sizes, int n_in,
                              void* d_out, int out_size, void* d_ws, size_t ws_size,
                              hipStream_t stream){
  const float* x    = (const float*)d_in[0];
  const int*   ei   = (const int*)d_in[1];
  const float* W1   = (const float*)d_in[2];
  const float* att1 = (const float*)d_in[3];
  const float* b1   = (const float*)d_in[4];
  const float* W2   = (const float*)d_in[5];
  const float* att2 = (const float*)d_in[6];
  const float* b2   = (const float*)d_in[7];
  int N = in_sizes[0] / 256;
  int E = in_sizes[1] / 2;
  const int* rows = ei;
  const int* cols = ei + E;
  float* out = (float*)d_out;

  char* p = (char*)d_ws;
  auto alloc = [&](size_t bytes)->void*{ void* q = p; p += (bytes + 255) & ~(size_t)255; return q; };
  int*      deg    = (int*)alloc((size_t)N*4);
  int*      cnt    = (int*)alloc((size_t)N*4);
  int*      cursor = (int*)alloc((size_t)N*4);
  int*      offs   = (int*)alloc((size_t)(N+1)*4);
  int*      bsum   = (int*)alloc(256*4);
  int*      csr    = (int*)alloc((size_t)(E+N)*4);
  float*    dinv   = (float*)alloc((size_t)N*4);
  float*    xt1    = (float*)alloc((size_t)N*128*4);
  unsigned* xtb    = (unsigned*)alloc((size_t)N*64*4);
  float*    sl1    = (float*)alloc((size_t)N*16);
  float*    sr1    = (float*)alloc((size_t)N*16);
  float*    hbuf   = (float*)alloc((size_t)N*128*4);
  unsigned* xt2b   = (unsigned*)alloc((size_t)N*8*4);
  float*    sl2    = (float*)alloc((size_t)N*4);
  float*    sr2    = (float*)alloc((size_t)N*4);
  short*    Whi    = (short*)alloc((size_t)128*256*2);
  short*    Wlo    = (short*)alloc((size_t)128*256*2);

  int gN   = (N + TPB - 1) / TPB;
  int gE   = (E + TPB - 1) / TPB;
  int gEN  = (E + N + TPB - 1) / TPB;
  int NB   = (N + 1023) / 1024;

  k_init<<<gN, TPB, 0, stream>>>(deg, cnt, cursor, N);
  k_count<<<gE, TPB, 0, stream>>>(rows, cols, deg, cnt, E);
  k_dinv<<<gN, TPB, 0, stream>>>(deg, dinv, N);
  k_scan_block<<<NB, 256, 0, stream>>>(cnt, bsum, N);
  k_scan_bsum<<<1, 256, 0, stream>>>(bsum, NB);
  k_scan_write<<<NB, 256, 0, stream>>>(cnt, bsum, offs, N);
  k_fill<<<gEN, TPB, 0, stream>>>(rows, cols, offs, cursor, csr, E, N);

  k_prepW<<<128, 256, 0, stream>>>(W1, Whi, Wlo);
  k_gemm1<<<(N + 127)/128, 256, 0, stream>>>(x, Whi, Wlo, xt1, xtb, N);
  k_sr1<<<(4*N + TPB - 1)/TPB, TPB, 0, stream>>>(xt1, att1, sl1, sr1, N);
  k_agg1<<<N, 64, 0, stream>>>(offs, csr, sl1, sr1, dinv, xtb, b1, hbuf, N);

  k_gemm2<<<(N + 15)/16, 256, 0, stream>>>(hbuf, W2, att2, xt2b, sl2, sr2, N);
  k_agg2<<<N, 64, 0, stream>>>(offs, csr, sl2, sr2, dinv, xt2b, b2, out, N);
}

// Round 6
// 600.285 us; speedup vs baseline: 1.7525x; 1.0525x over previous
//
#include <hip/hip_runtime.h>
#include <math.h>

#define TPB 256
#define NR 8   // histogram replicas (atomic line-contention spreading)

__device__ __forceinline__ float lrelu(float a){ return a >= 0.f ? a : 0.2f*a; }

typedef __attribute__((ext_vector_type(8))) short bf16x8;
typedef __attribute__((ext_vector_type(4))) float f32x4;

// round-to-nearest-even fp32 -> bf16 bits
__device__ __forceinline__ unsigned short bfr(float f){
  unsigned u = __float_as_uint(f);
  return (unsigned short)((u + 0x7fffu + ((u >> 16) & 1u)) >> 16);
}

// ---------------- graph degree / CSR build (8-way replicated histograms) ----------------

__global__ void k_init(int* degR, int* cntR, int* cursorR, int N, int E){
  int i = blockIdx.x*TPB + threadIdx.x;
  if(i >= N) return;
  int ri = ((unsigned)(E + i) >> 8) & (NR-1);   // self-loop edge id E+i -> replica
  #pragma unroll
  for(int r=0;r<NR;r++){
    degR[r*N+i] = 0;
    cntR[r*N+i] = (r==ri) ? 1 : 0;    // seed self-loop in its replica
    cursorR[r*N+i] = 0;
  }
}

__global__ void k_count(const int* __restrict__ rows, const int* __restrict__ cols,
                        int* degR, int* cntR, int E, int N){
  int e = blockIdx.x*TPB + threadIdx.x;
  if(e < E){
    int r = ((unsigned)e >> 8) & (NR-1);
    atomicAdd(&degR[r*N + rows[e]], 1);   // degree over ROW (source) per gcn_norm
    atomicAdd(&cntR[r*N + cols[e]], 1);   // CSR counts over COL (target)
  }
}

// sum replicas -> cnt, per-replica exclusive bases -> baseR, fused dinv
__global__ void k_reduce(const int* __restrict__ degR, const int* __restrict__ cntR,
                         int* __restrict__ baseR, int* __restrict__ cnt,
                         float* __restrict__ dinv, int N){
  int i = blockIdx.x*TPB + threadIdx.x;
  if(i >= N) return;
  int bc = 0;
  #pragma unroll
  for(int r=0;r<NR;r++){ baseR[r*N+i] = bc; bc += cntR[r*N+i]; }
  cnt[i] = bc;
  int ds = 1;                            // self-loop
  #pragma unroll
  for(int r=0;r<NR;r++) ds += degR[r*N+i];
  dinv[i] = 1.f / sqrtf((float)ds);
}

// exclusive scan of cnt[0..N) into offs[0..N], 1024 elements per block
__global__ void k_scan_block(const int* __restrict__ cnt, int* __restrict__ bsum, int N){
  __shared__ int sdata[256];
  int base = blockIdx.x*1024 + threadIdx.x*4;
  int s = 0;
  #pragma unroll
  for(int i=0;i<4;i++){ int idx = base+i; if(idx < N) s += cnt[idx]; }
  sdata[threadIdx.x] = s; __syncthreads();
  for(int off=128; off>0; off>>=1){
    if(threadIdx.x < off) sdata[threadIdx.x] += sdata[threadIdx.x+off];
    __syncthreads();
  }
  if(threadIdx.x == 0) bsum[blockIdx.x] = sdata[0];
}

__global__ void k_scan_bsum(int* bsum, int NB){
  __shared__ int s[256];
  int t = threadIdx.x;
  int v = (t < NB) ? bsum[t] : 0;
  s[t] = v; __syncthreads();
  for(int off=1; off<256; off<<=1){
    int add = (t >= off) ? s[t-off] : 0;
    __syncthreads();
    s[t] += add;
    __syncthreads();
  }
  if(t < NB) bsum[t] = s[t] - v;   // exclusive
}

__global__ void k_scan_write(const int* __restrict__ cnt, const int* __restrict__ bsum,
                             int* __restrict__ offs, int N){
  __shared__ int sdata[256];
  int t = threadIdx.x;
  int base = blockIdx.x*1024 + t*4;
  int v[4]; int s = 0;
  #pragma unroll
  for(int i=0;i<4;i++){ int idx = base+i; v[i] = (idx < N) ? cnt[idx] : 0; s += v[i]; }
  sdata[t] = s; __syncthreads();
  int mine = s;
  for(int off=1; off<256; off<<=1){
    int add = (t >= off) ? sdata[t-off] : 0;
    __syncthreads();
    sdata[t] += add;
    __syncthreads();
  }
  int run = sdata[t] - mine + bsum[blockIdx.x];
  #pragma unroll
  for(int i=0;i<4;i++){
    int idx = base+i;
    if(idx < N){
      offs[idx] = run;
      run += v[i];
      if(idx == N-1) offs[N] = run;
    }
  }
}

__global__ void k_fill(const int* __restrict__ rows, const int* __restrict__ cols,
                       const int* __restrict__ offs, const int* __restrict__ baseR,
                       int* cursorR, int* __restrict__ csr_src, int E, int N){
  int e = blockIdx.x*TPB + threadIdx.x;
  if(e >= E + N) return;
  int r = ((unsigned)e >> 8) & (NR-1);
  int rr, c;
  if(e < E){ rr = rows[e]; c = cols[e]; } else { rr = c = e - E; }
  int pos = offs[c] + baseR[r*N+c] + atomicAdd(&cursorR[r*N+c], 1);
  csr_src[pos] = rr;
}

// ---------------- W1 prep: transpose + bf16 hi/lo split ----------------

__global__ void k_prepW(const float* __restrict__ W, short* __restrict__ Whi,
                        short* __restrict__ Wlo){
  int idx = blockIdx.x*256 + threadIdx.x;   // 32768
  int n = idx >> 8, k = idx & 255;
  float f = W[k*128 + n];
  unsigned short h = bfr(f);
  float hf = __uint_as_float(((unsigned)h) << 16);
  Whi[n*256 + k] = (short)h;
  Wlo[n*256 + k] = (short)bfr(f - hf);
}

// ---------------- layer 1 GEMM via split-bf16 MFMA ----------------
// xt1 = x @ W1. Also emits xtb: bf16 channel pairs (c, c+32) packed per dword
// (gather payload for k_agg1), straight from accumulator registers.

#define SA 40
__global__ __launch_bounds__(256) void k_gemm1(const float* __restrict__ x,
    const short* __restrict__ Whi, const short* __restrict__ Wlo,
    float* __restrict__ xt, unsigned* __restrict__ xtb, int N){
  __shared__ __align__(16) short Ah[128*SA];
  __shared__ __align__(16) short Al[128*SA];
  __shared__ __align__(16) short Bh[128*SA];
  __shared__ __align__(16) short Bl[128*SA];
  const float4* x4 = (const float4*)x;
  int tid = threadIdx.x;
  int n0 = blockIdx.x * 128;
  int w = tid >> 6, l = tid & 63;
  int wm = w & 1, wn = w >> 1;
  int lm = l & 15, lq = l >> 4;

  f32x4 acc[4][4];
  #pragma unroll
  for(int a=0;a<4;a++)
    #pragma unroll
    for(int b=0;b<4;b++) acc[a][b] = (f32x4){0.f,0.f,0.f,0.f};

  for(int c=0;c<8;c++){
    #pragma unroll
    for(int i=0;i<4;i++){
      int idx = tid + 256*i;
      int r = idx >> 3, kq = idx & 7;
      int row = n0 + r;
      float4 v = make_float4(0.f,0.f,0.f,0.f);
      if(row < N) v = x4[(size_t)row*64 + c*8 + kq];
      unsigned short h0=bfr(v.x), h1=bfr(v.y), h2=bfr(v.z), h3=bfr(v.w);
      float l0 = v.x - __uint_as_float(((unsigned)h0)<<16);
      float l1 = v.y - __uint_as_float(((unsigned)h1)<<16);
      float l2 = v.z - __uint_as_float(((unsigned)h2)<<16);
      float l3 = v.w - __uint_as_float(((unsigned)h3)<<16);
      unsigned hi01 = (unsigned)h0 | ((unsigned)h1<<16);
      unsigned hi23 = (unsigned)h2 | ((unsigned)h3<<16);
      unsigned lo01 = (unsigned)bfr(l0) | ((unsigned)bfr(l1)<<16);
      unsigned lo23 = (unsigned)bfr(l2) | ((unsigned)bfr(l3)<<16);
      *((uint2*)&Ah[r*SA + kq*4]) = make_uint2(hi01, hi23);
      *((uint2*)&Al[r*SA + kq*4]) = make_uint2(lo01, lo23);
    }
    #pragma unroll
    for(int i=0;i<2;i++){
      int idx = tid + 256*i;
      int r = idx >> 2, q = idx & 3;
      *((uint4*)&Bh[r*SA + q*8]) = *((const uint4*)(Whi + r*256 + c*32 + q*8));
      *((uint4*)&Bl[r*SA + q*8]) = *((const uint4*)(Wlo + r*256 + c*32 + q*8));
    }
    __syncthreads();
    bf16x8 ah[4], al[4];
    #pragma unroll
    for(int mt=0;mt<4;mt++){
      int rr = wm*64 + mt*16 + lm;
      ah[mt] = *((bf16x8*)&Ah[rr*SA + lq*8]);
      al[mt] = *((bf16x8*)&Al[rr*SA + lq*8]);
    }
    #pragma unroll
    for(int nt=0;nt<4;nt++){
      int rr = wn*64 + nt*16 + lm;
      bf16x8 bh = *((bf16x8*)&Bh[rr*SA + lq*8]);
      bf16x8 bl = *((bf16x8*)&Bl[rr*SA + lq*8]);
      #pragma unroll
      for(int mt=0;mt<4;mt++){
        acc[mt][nt] = __builtin_amdgcn_mfma_f32_16x16x32_bf16(ah[mt], bh, acc[mt][nt], 0,0,0);
        acc[mt][nt] = __builtin_amdgcn_mfma_f32_16x16x32_bf16(ah[mt], bl, acc[mt][nt], 0,0,0);
        acc[mt][nt] = __builtin_amdgcn_mfma_f32_16x16x32_bf16(al[mt], bh, acc[mt][nt], 0,0,0);
      }
    }
    __syncthreads();
  }
  // epilogue: C/D layout col=lane&15, row=lq*4+reg.
  #pragma unroll
  for(int mt=0;mt<4;mt++){
    #pragma unroll
    for(int v=0;v<4;v++){
      int row = n0 + wm*64 + mt*16 + lq*4 + v;
      if(row < N){
        #pragma unroll
        for(int nt=0;nt<4;nt++)
          xt[(size_t)row*128 + wn*64 + nt*16 + lm] = acc[mt][nt][v];
        unsigned p0 = (unsigned)bfr(acc[mt][0][v]) | ((unsigned)bfr(acc[mt][2][v])<<16);
        unsigned p1 = (unsigned)bfr(acc[mt][1][v]) | ((unsigned)bfr(acc[mt][3][v])<<16);
        int jb = wn*32 + lm;
        xtb[(size_t)row*64 + jb]      = p0;
        xtb[(size_t)row*64 + jb + 16] = p1;
      }
    }
  }
}

// per-node attention scalars, layer 1: s_l[n,h], s_r[n,h]
__global__ void k_sr1(const float* __restrict__ xt, const float* __restrict__ att1,
                      float* __restrict__ sl, float* __restrict__ sr, int N){
  int i = blockIdx.x*TPB + threadIdx.x;   // i = n*4 + h
  if(i >= N*4) return;
  int n = i >> 2, hh = i & 3;
  const float* xp = xt + (size_t)n*128 + hh*32;
  const float* al = att1 + hh*64;
  const float* ar = al + 32;
  float a = 0.f, b = 0.f;
  #pragma unroll
  for(int c=0;c<32;c++){ float v = xp[c]; a += v*al[c]; b += v*ar[c]; }
  sl[i] = a; sr[i] = b;
}

// ---------------- layer 1 aggregation: one wave per target node ----------------
// bf16-pair payload (1 dword/lane/edge), 8-deep unrolled gather for MLP.

__global__ __launch_bounds__(64) void k_agg1(const int* __restrict__ offs, const int* __restrict__ srcs,
    const float* __restrict__ sl, const float* __restrict__ sr, const float* __restrict__ dinv,
    const unsigned* __restrict__ xtb, const float* __restrict__ b1, float* __restrict__ h, int N){
  __shared__ int   s_sh[64];
  __shared__ float w_sh[64*4];
  int n = blockIdx.x;
  if(n >= N) return;
  int lane = threadIdx.x;
  int beg = offs[n], end = offs[n+1];
  float4 sln = *((const float4*)(sl + (size_t)n*4));
  float m0=-1e30f,m1=-1e30f,m2=-1e30f,m3=-1e30f;
  for(int j=beg+lane; j<end; j+=64){
    int s = srcs[j];
    float4 a = *((const float4*)(sr + (size_t)s*4));
    m0 = fmaxf(m0, lrelu(sln.x + a.x));
    m1 = fmaxf(m1, lrelu(sln.y + a.y));
    m2 = fmaxf(m2, lrelu(sln.z + a.z));
    m3 = fmaxf(m3, lrelu(sln.w + a.w));
  }
  #pragma unroll
  for(int o=32;o>0;o>>=1){
    m0 = fmaxf(m0, __shfl_xor(m0,o));
    m1 = fmaxf(m1, __shfl_xor(m1,o));
    m2 = fmaxf(m2, __shfl_xor(m2,o));
    m3 = fmaxf(m3, __shfl_xor(m3,o));
  }
  int h0 = lane >> 5;
  float den0=0.f,den1=0.f,den2=0.f,den3=0.f;
  float acc0=0.f, acc1=0.f;
  for(int c0=beg; c0<end; c0+=64){
    int cnt = min(64, end-c0);
    int j = c0 + lane;
    float e0=0.f,e1=0.f,e2=0.f,e3=0.f, wd=0.f; int s=0;
    if(j<end){
      s = srcs[j];
      float4 a = *((const float4*)(sr + (size_t)s*4));
      e0 = __expf(lrelu(sln.x + a.x) - m0);
      e1 = __expf(lrelu(sln.y + a.y) - m1);
      e2 = __expf(lrelu(sln.z + a.z) - m2);
      e3 = __expf(lrelu(sln.w + a.w) - m3);
      wd = dinv[s];
    }
    den0+=e0; den1+=e1; den2+=e2; den3+=e3;
    s_sh[lane] = s;
    w_sh[lane*4+0] = wd*e0;
    w_sh[lane*4+1] = wd*e1;
    w_sh[lane*4+2] = wd*e2;
    w_sh[lane*4+3] = wd*e3;
    __syncthreads();
    int k = 0;
    for(; k+8<=cnt; k+=8){
      int sk[8];
      #pragma unroll
      for(int u=0;u<8;u++) sk[u] = __builtin_amdgcn_readfirstlane(s_sh[k+u]);
      unsigned pv[8];
      #pragma unroll
      for(int u=0;u<8;u++) pv[u] = xtb[(size_t)sk[u]*64 + lane];
      #pragma unroll
      for(int u=0;u<8;u++){
        float2 wv = *((const float2*)&w_sh[(k+u)*4 + h0*2]);
        acc0 += wv.x * __uint_as_float(pv[u] << 16);
        acc1 += wv.y * __uint_as_float(pv[u] & 0xffff0000u);
      }
    }
    for(; k<cnt; k++){
      int sk = __builtin_amdgcn_readfirstlane(s_sh[k]);
      unsigned pvv = xtb[(size_t)sk*64 + lane];
      float2 wv = *((const float2*)&w_sh[k*4 + h0*2]);
      acc0 += wv.x * __uint_as_float(pvv << 16);
      acc1 += wv.y * __uint_as_float(pvv & 0xffff0000u);
    }
    __syncthreads();
  }
  #pragma unroll
  for(int o=32;o>0;o>>=1){
    den0 += __shfl_xor(den0,o);
    den1 += __shfl_xor(den1,o);
    den2 += __shfl_xor(den2,o);
    den3 += __shfl_xor(den3,o);
  }
  float din = dinv[n];
  int ch0 = (lane < 32) ? lane : lane + 32;   // pairs (c, c+32)
  int ch1 = ch0 + 32;
  float d0 = (lane < 32) ? den0 : den2;
  float d1 = (lane < 32) ? den1 : den3;
  float o0 = din*acc0/(d0 + 1e-16f) + b1[ch0];
  float o1 = din*acc1/(d1 + 1e-16f) + b1[ch1];
  h[(size_t)n*128 + ch0] = o0 > 0.f ? o0 : 0.f;
  h[(size_t)n*128 + ch1] = o1 > 0.f ? o1 : 0.f;
}

// ---------------- layer 2 GEMM (128->16) + attention scalars, bf16-pair payload ----------------

__global__ __launch_bounds__(256) void k_gemm2(const float* __restrict__ hmat, const float* __restrict__ W2,
    const float* __restrict__ att2, unsigned* __restrict__ xt2b,
    float* __restrict__ sl2, float* __restrict__ sr2, int N){
  __shared__ float hs[16*132];
  __shared__ float ws[16*132];
  __shared__ float xs[16*16];
  int t = threadIdx.x;
  int n0 = blockIdx.x * 16;
  #pragma unroll
  for(int i=0;i<8;i++){
    int idx = t + 256*i;
    int k = idx >> 4, c = idx & 15;
    ws[c*132 + k] = W2[idx];
  }
  #pragma unroll
  for(int i=0;i<2;i++){
    int idx = t + 256*i;
    int r = idx >> 5, k4 = idx & 31;
    int n = n0 + r;
    float4 v = make_float4(0.f,0.f,0.f,0.f);
    if(n < N) v = ((const float4*)hmat)[(size_t)n*32 + k4];
    *((float4*)&hs[r*132 + k4*4]) = v;
  }
  __syncthreads();
  int r = t >> 4, c = t & 15;
  float acc = 0.f;
  for(int k=0;k<128;k+=4){
    float4 hv = *((const float4*)&hs[r*132+k]);
    float4 wv = *((const float4*)&ws[c*132+k]);
    acc += hv.x*wv.x + hv.y*wv.y + hv.z*wv.z + hv.w*wv.w;
  }
  xs[r*16 + c] = acc;
  __syncthreads();
  int n = n0 + r;
  if(c < 8 && n < N){
    unsigned pk = (unsigned)bfr(xs[r*16+c]) | ((unsigned)bfr(xs[r*16+c+8])<<16);
    xt2b[(size_t)n*8 + c] = pk;
  }
  if(t < 16){
    int nn = n0 + t;
    if(nn < N){
      float a = 0.f, b = 0.f;
      #pragma unroll
      for(int cc=0;cc<16;cc++){ float v = xs[t*16+cc]; a += v*att2[cc]; b += v*att2[16+cc]; }
      sl2[nn] = a; sr2[nn] = b;
    }
  }
}

// ---------------- layer 2 aggregation: 8 edge-groups x 8 channel-lanes ----------------

__global__ __launch_bounds__(64) void k_agg2(const int* __restrict__ offs, const int* __restrict__ srcs,
    const float* __restrict__ sl2, const float* __restrict__ sr2, const float* __restrict__ dinv,
    const unsigned* __restrict__ xt2b, const float* __restrict__ b2, float* __restrict__ out, int N){
  __shared__ int   s_sh[64];
  __shared__ float w_sh[64];
  int n = blockIdx.x;
  if(n >= N) return;
  int lane = threadIdx.x;
  int beg = offs[n], end = offs[n+1];
  float sln = sl2[n];
  float m = -1e30f;
  for(int j=beg+lane; j<end; j+=64)
    m = fmaxf(m, lrelu(sln + sr2[srcs[j]]));
  #pragma unroll
  for(int o=32;o>0;o>>=1) m = fmaxf(m, __shfl_xor(m,o));
  float den = 0.f, acc0 = 0.f, acc1 = 0.f;
  int grp = lane >> 3, ch = lane & 7;
  for(int c0=beg; c0<end; c0+=64){
    int cnt = min(64, end-c0);
    int j = c0 + lane;
    float e=0.f, wd=0.f; int s=0;
    if(j<end){
      s = srcs[j];
      e = __expf(lrelu(sln + sr2[s]) - m);
      wd = dinv[s];
    }
    den += e;
    s_sh[lane] = s;
    w_sh[lane] = wd*e;
    __syncthreads();
    for(int k=0;k<cnt;k+=8){
      int kk = k + grp;
      if(kk < cnt){
        int sk = s_sh[kk];
        float wk = w_sh[kk];
        unsigned pv = xt2b[(size_t)sk*8 + ch];
        acc0 += wk * __uint_as_float(pv << 16);
        acc1 += wk * __uint_as_float(pv & 0xffff0000u);
      }
    }
    __syncthreads();
  }
  #pragma unroll
  for(int o=32;o>0;o>>=1) den += __shfl_xor(den,o);
  acc0 += __shfl_xor(acc0,8);  acc0 += __shfl_xor(acc0,16);  acc0 += __shfl_xor(acc0,32);
  acc1 += __shfl_xor(acc1,8);  acc1 += __shfl_xor(acc1,16);  acc1 += __shfl_xor(acc1,32);
  if(lane < 8){
    float din = dinv[n];
    out[(size_t)n*16 + lane]     = din*acc0/(den + 1e-16f) + b2[lane];
    out[(size_t)n*16 + lane + 8] = din*acc1/(den + 1e-16f) + b2[lane+8];
  }
}

// ---------------- host launch ----------------

extern "C" void kernel_launch(void* const* d_in, const int* in_sizes, int n_in,
                              void* d_out, int out_size, void* d_ws, size_t ws_size,
                              hipStream_t stream){
  const float* x    = (const float*)d_in[0];
  const int*   ei   = (const int*)d_in[1];
  const float* W1   = (const float*)d_in[2];
  const float* att1 = (const float*)d_in[3];
  const float* b1   = (const float*)d_in[4];
  const float* W2   = (const float*)d_in[5];
  const float* att2 = (const float*)d_in[6];
  const float* b2   = (const float*)d_in[7];
  int N = in_sizes[0] / 256;
  int E = in_sizes[1] / 2;
  const int* rows = ei;
  const int* cols = ei + E;
  float* out = (float*)d_out;

  char* p = (char*)d_ws;
  auto alloc = [&](size_t bytes)->void*{ void* q = p; p += (bytes + 255) & ~(size_t)255; return q; };
  int*      cnt     = (int*)alloc((size_t)N*4);
  int*      degR    = (int*)alloc((size_t)NR*N*4);
  int*      cntR    = (int*)alloc((size_t)NR*N*4);
  int*      baseR   = (int*)alloc((size_t)NR*N*4);
  int*      cursorR = (int*)alloc((size_t)NR*N*4);
  int*      offs    = (int*)alloc((size_t)(N+1)*4);
  int*      bsum    = (int*)alloc(256*4);
  int*      csr     = (int*)alloc((size_t)(E+N)*4);
  float*    dinv    = (float*)alloc((size_t)N*4);
  float*    xt1     = (float*)alloc((size_t)N*128*4);
  unsigned* xtb     = (unsigned*)alloc((size_t)N*64*4);
  float*    sl1     = (float*)alloc((size_t)N*16);
  float*    sr1     = (float*)alloc((size_t)N*16);
  float*    hbuf    = (float*)alloc((size_t)N*128*4);
  unsigned* xt2b    = (unsigned*)alloc((size_t)N*8*4);
  float*    sl2     = (float*)alloc((size_t)N*4);
  float*    sr2     = (float*)alloc((size_t)N*4);
  short*    Whi     = (short*)alloc((size_t)128*256*2);
  short*    Wlo     = (short*)alloc((size_t)128*256*2);

  int gN   = (N + TPB - 1) / TPB;
  int gE   = (E + TPB - 1) / TPB;
  int gEN  = (E + N + TPB - 1) / TPB;
  int NB   = (N + 1023) / 1024;

  k_init<<<gN, TPB, 0, stream>>>(degR, cntR, cursorR, N, E);
  k_count<<<gE, TPB, 0, stream>>>(rows, cols, degR, cntR, E, N);
  k_reduce<<<gN, TPB, 0, stream>>>(degR, cntR, baseR, cnt, dinv, N);
  k_scan_block<<<NB, 256, 0, stream>>>(cnt, bsum, N);
  k_scan_bsum<<<1, 256, 0, stream>>>(bsum, NB);
  k_scan_write<<<NB, 256, 0, stream>>>(cnt, bsum, offs, N);
  k_fill<<<gEN, TPB, 0, stream>>>(rows, cols, offs, baseR, cursorR, csr, E, N);

  k_prepW<<<128, 256, 0, stream>>>(W1, Whi, Wlo);
  k_gemm1<<<(N + 127)/128, 256, 0, stream>>>(x, Whi, Wlo, xt1, xtb, N);
  k_sr1<<<(4*N + TPB - 1)/TPB, TPB, 0, stream>>>(xt1, att1, sl1, sr1, N);
  k_agg1<<<N, 64, 0, stream>>>(offs, csr, sl1, sr1, dinv, xtb, b1, hbuf, N);

  k_gemm2<<<(N + 15)/16, 256, 0, stream>>>(hbuf, W2, att2, xt2b, sl2, sr2, N);
  k_agg2<<<N, 64, 0, stream>>>(offs, csr, sl2, sr2, dinv, xt2b, b2, out, N);
}

// Round 7
// 561.733 us; speedup vs baseline: 1.8727x; 1.0686x over previous
//
#include <hip/hip_runtime.h>
#include <math.h>

#define TPB 256
#define SEGSZ 16384
#define SEGSH 14
#define NCHUNK 64

__device__ __forceinline__ float lrelu(float a){ return a >= 0.f ? a : 0.2f*a; }

typedef __attribute__((ext_vector_type(8))) short bf16x8;
typedef __attribute__((ext_vector_type(4))) float f32x4;

// round-to-nearest-even fp32 -> bf16 bits
__device__ __forceinline__ unsigned short bfr(float f){
  unsigned u = __float_as_uint(f);
  return (unsigned short)((u + 0x7fffu + ((u >> 16) & 1u)) >> 16);
}

// ---------------- graph build: LDS segmented histogram, atomic-free CSR ----------------
// Virtual edge stream of length ET=E+N: e<E -> (rows[e],cols[e]); e>=E -> self-loop (e-E,e-E).
// Block (seg,chunk): stream chunk's targets, LDS-count those in segment; the atomicAdd
// return value is the edge's rank within (seg,chunk,node) -> enables atomic-free fill.

template<bool WITH_RANK>
__global__ __launch_bounds__(256) void k_hist(const int* __restrict__ idxs,
    unsigned short* __restrict__ rank16, int* __restrict__ partial,
    int E, int N, int ET, int CS){
  __shared__ int hist[SEGSZ];
  int seg = blockIdx.x / NCHUNK, chunk = blockIdx.x % NCHUNK;
  for(int i=threadIdx.x; i<SEGSZ; i+=256) hist[i] = 0;
  __syncthreads();
  int lo = seg << SEGSH;
  int e0 = chunk*CS, e1 = min(e0+CS, ET);
  for(int e=e0+threadIdx.x; e<e1; e+=256){
    int v = (e < E) ? idxs[e] : e - E;
    int li = v - lo;
    if((unsigned)li < SEGSZ){
      int r = atomicAdd(&hist[li], 1);
      if(WITH_RANK) rank16[e] = (unsigned short)r;
    }
  }
  __syncthreads();
  int base = (seg*NCHUNK + chunk)*SEGSZ;
  int lim = min(SEGSZ, N - lo);
  for(int i=threadIdx.x; i<lim; i+=256) partial[base+i] = hist[i];
}

// sum both slabs: deg -> dinv, cnt -> cnt
__global__ void k_red2(const int* __restrict__ pd, const int* __restrict__ pc,
                       int* __restrict__ cnt, float* __restrict__ dinv, int N){
  int i = blockIdx.x*TPB + threadIdx.x;
  if(i >= N) return;
  int s = i >> SEGSH, li = i & (SEGSZ-1);
  int b = s*NCHUNK*SEGSZ + li;
  int sd = 0, sc = 0;
  #pragma unroll 8
  for(int c=0;c<NCHUNK;c++){ sd += pd[b + c*SEGSZ]; sc += pc[b + c*SEGSZ]; }
  cnt[i] = sc;
  dinv[i] = 1.f / sqrtf((float)sd);
}

// exclusive scan of cnt[0..N) into offs[0..N], 1024 elements per block
__global__ void k_scan_block(const int* __restrict__ cnt, int* __restrict__ bsum, int N){
  __shared__ int sdata[256];
  int base = blockIdx.x*1024 + threadIdx.x*4;
  int s = 0;
  #pragma unroll
  for(int i=0;i<4;i++){ int idx = base+i; if(idx < N) s += cnt[idx]; }
  sdata[threadIdx.x] = s; __syncthreads();
  for(int off=128; off>0; off>>=1){
    if(threadIdx.x < off) sdata[threadIdx.x] += sdata[threadIdx.x+off];
    __syncthreads();
  }
  if(threadIdx.x == 0) bsum[blockIdx.x] = sdata[0];
}

__global__ void k_scan_bsum(int* bsum, int NB){
  __shared__ int s[256];
  int t = threadIdx.x;
  int v = (t < NB) ? bsum[t] : 0;
  s[t] = v; __syncthreads();
  for(int off=1; off<256; off<<=1){
    int add = (t >= off) ? s[t-off] : 0;
    __syncthreads();
    s[t] += add;
    __syncthreads();
  }
  if(t < NB) bsum[t] = s[t] - v;   // exclusive
}

__global__ void k_scan_write(const int* __restrict__ cnt, const int* __restrict__ bsum,
                             int* __restrict__ offs, int N){
  __shared__ int sdata[256];
  int t = threadIdx.x;
  int base = blockIdx.x*1024 + t*4;
  int v[4]; int s = 0;
  #pragma unroll
  for(int i=0;i<4;i++){ int idx = base+i; v[i] = (idx < N) ? cnt[idx] : 0; s += v[i]; }
  sdata[t] = s; __syncthreads();
  int mine = s;
  for(int off=1; off<256; off<<=1){
    int add = (t >= off) ? sdata[t-off] : 0;
    __syncthreads();
    sdata[t] += add;
    __syncthreads();
  }
  int run = sdata[t] - mine + bsum[blockIdx.x];
  #pragma unroll
  for(int i=0;i<4;i++){
    int idx = base+i;
    if(idx < N){
      offs[idx] = run;
      run += v[i];
      if(idx == N-1) offs[N] = run;
    }
  }
}

// rewrite cnt-slab in place: partial[s][c][i] <- offs[i] + exclusive-prefix over c
__global__ void k_rebase(int* __restrict__ pc, const int* __restrict__ offs, int N){
  int i = blockIdx.x*TPB + threadIdx.x;
  if(i >= N) return;
  int s = i >> SEGSH, li = i & (SEGSZ-1);
  int b = s*NCHUNK*SEGSZ + li;
  int run = offs[i];
  #pragma unroll 8
  for(int c=0;c<NCHUNK;c++){
    int idx = b + c*SEGSZ;
    int t = pc[idx];
    pc[idx] = run;
    run += t;
  }
}

// atomic-free fill: pos = base(seg,chunk,node) + rank
__global__ void k_fill2(const int* __restrict__ rows, const int* __restrict__ cols,
                        const unsigned short* __restrict__ rank16,
                        const int* __restrict__ pc, int* __restrict__ csr,
                        int E, int N, int ET, int CS){
  int e = blockIdx.x*TPB + threadIdx.x;
  if(e >= ET) return;
  int v, r;
  if(e < E){ v = cols[e]; r = rows[e]; } else { v = r = e - E; }
  int s = v >> SEGSH, li = v & (SEGSZ-1);
  int chunk = e / CS;
  int pos = pc[(s*NCHUNK + chunk)*SEGSZ + li] + (int)rank16[e];
  csr[pos] = r;
}

// ---------------- W1 prep: transpose + bf16 hi/lo split ----------------

__global__ void k_prepW(const float* __restrict__ W, short* __restrict__ Whi,
                        short* __restrict__ Wlo){
  int idx = blockIdx.x*256 + threadIdx.x;   // 32768
  int n = idx >> 8, k = idx & 255;
  float f = W[k*128 + n];
  unsigned short h = bfr(f);
  float hf = __uint_as_float(((unsigned)h) << 16);
  Whi[n*256 + k] = (short)h;
  Wlo[n*256 + k] = (short)bfr(f - hf);
}

// ---------------- layer 1 GEMM via split-bf16 MFMA ----------------
// xt1 = x @ W1. Also emits xtb: bf16 channel pairs (c, c+32) packed per dword.

#define SA 40
__global__ __launch_bounds__(256) void k_gemm1(const float* __restrict__ x,
    const short* __restrict__ Whi, const short* __restrict__ Wlo,
    float* __restrict__ xt, unsigned* __restrict__ xtb, int N){
  __shared__ __align__(16) short Ah[128*SA];
  __shared__ __align__(16) short Al[128*SA];
  __shared__ __align__(16) short Bh[128*SA];
  __shared__ __align__(16) short Bl[128*SA];
  const float4* x4 = (const float4*)x;
  int tid = threadIdx.x;
  int n0 = blockIdx.x * 128;
  int w = tid >> 6, l = tid & 63;
  int wm = w & 1, wn = w >> 1;
  int lm = l & 15, lq = l >> 4;

  f32x4 acc[4][4];
  #pragma unroll
  for(int a=0;a<4;a++)
    #pragma unroll
    for(int b=0;b<4;b++) acc[a][b] = (f32x4){0.f,0.f,0.f,0.f};

  for(int c=0;c<8;c++){
    #pragma unroll
    for(int i=0;i<4;i++){
      int idx = tid + 256*i;
      int r = idx >> 3, kq = idx & 7;
      int row = n0 + r;
      float4 v = make_float4(0.f,0.f,0.f,0.f);
      if(row < N) v = x4[(size_t)row*64 + c*8 + kq];
      unsigned short h0=bfr(v.x), h1=bfr(v.y), h2=bfr(v.z), h3=bfr(v.w);
      float l0 = v.x - __uint_as_float(((unsigned)h0)<<16);
      float l1 = v.y - __uint_as_float(((unsigned)h1)<<16);
      float l2 = v.z - __uint_as_float(((unsigned)h2)<<16);
      float l3 = v.w - __uint_as_float(((unsigned)h3)<<16);
      unsigned hi01 = (unsigned)h0 | ((unsigned)h1<<16);
      unsigned hi23 = (unsigned)h2 | ((unsigned)h3<<16);
      unsigned lo01 = (unsigned)bfr(l0) | ((unsigned)bfr(l1)<<16);
      unsigned lo23 = (unsigned)bfr(l2) | ((unsigned)bfr(l3)<<16);
      *((uint2*)&Ah[r*SA + kq*4]) = make_uint2(hi01, hi23);
      *((uint2*)&Al[r*SA + kq*4]) = make_uint2(lo01, lo23);
    }
    #pragma unroll
    for(int i=0;i<2;i++){
      int idx = tid + 256*i;
      int r = idx >> 2, q = idx & 3;
      *((uint4*)&Bh[r*SA + q*8]) = *((const uint4*)(Whi + r*256 + c*32 + q*8));
      *((uint4*)&Bl[r*SA + q*8]) = *((const uint4*)(Wlo + r*256 + c*32 + q*8));
    }
    __syncthreads();
    bf16x8 ah[4], al[4];
    #pragma unroll
    for(int mt=0;mt<4;mt++){
      int rr = wm*64 + mt*16 + lm;
      ah[mt] = *((bf16x8*)&Ah[rr*SA + lq*8]);
      al[mt] = *((bf16x8*)&Al[rr*SA + lq*8]);
    }
    #pragma unroll
    for(int nt=0;nt<4;nt++){
      int rr = wn*64 + nt*16 + lm;
      bf16x8 bh = *((bf16x8*)&Bh[rr*SA + lq*8]);
      bf16x8 bl = *((bf16x8*)&Bl[rr*SA + lq*8]);
      #pragma unroll
      for(int mt=0;mt<4;mt++){
        acc[mt][nt] = __builtin_amdgcn_mfma_f32_16x16x32_bf16(ah[mt], bh, acc[mt][nt], 0,0,0);
        acc[mt][nt] = __builtin_amdgcn_mfma_f32_16x16x32_bf16(ah[mt], bl, acc[mt][nt], 0,0,0);
        acc[mt][nt] = __builtin_amdgcn_mfma_f32_16x16x32_bf16(al[mt], bh, acc[mt][nt], 0,0,0);
      }
    }
    __syncthreads();
  }
  // epilogue: C/D layout col=lane&15, row=lq*4+reg.
  #pragma unroll
  for(int mt=0;mt<4;mt++){
    #pragma unroll
    for(int v=0;v<4;v++){
      int row = n0 + wm*64 + mt*16 + lq*4 + v;
      if(row < N){
        #pragma unroll
        for(int nt=0;nt<4;nt++)
          xt[(size_t)row*128 + wn*64 + nt*16 + lm] = acc[mt][nt][v];
        unsigned p0 = (unsigned)bfr(acc[mt][0][v]) | ((unsigned)bfr(acc[mt][2][v])<<16);
        unsigned p1 = (unsigned)bfr(acc[mt][1][v]) | ((unsigned)bfr(acc[mt][3][v])<<16);
        int jb = wn*32 + lm;
        xtb[(size_t)row*64 + jb]      = p0;
        xtb[(size_t)row*64 + jb + 16] = p1;
      }
    }
  }
}

// per-node attention scalars, layer 1: s_l[n,h], s_r[n,h]
__global__ void k_sr1(const float* __restrict__ xt, const float* __restrict__ att1,
                      float* __restrict__ sl, float* __restrict__ sr, int N){
  int i = blockIdx.x*TPB + threadIdx.x;   // i = n*4 + h
  if(i >= N*4) return;
  int n = i >> 2, hh = i & 3;
  const float* xp = xt + (size_t)n*128 + hh*32;
  const float* al = att1 + hh*64;
  const float* ar = al + 32;
  float a = 0.f, b = 0.f;
  #pragma unroll
  for(int c=0;c<32;c++){ float v = xp[c]; a += v*al[c]; b += v*ar[c]; }
  sl[i] = a; sr[i] = b;
}

// ---------------- layer 1 aggregation: one wave per target node ----------------
// bf16-pair payload (1 dword/lane/edge), 8-deep unrolled gather for MLP.

__global__ __launch_bounds__(64) void k_agg1(const int* __restrict__ offs, const int* __restrict__ srcs,
    const float* __restrict__ sl, const float* __restrict__ sr, const float* __restrict__ dinv,
    const unsigned* __restrict__ xtb, const float* __restrict__ b1, float* __restrict__ h, int N){
  __shared__ int   s_sh[64];
  __shared__ float w_sh[64*4];
  int n = blockIdx.x;
  if(n >= N) return;
  int lane = threadIdx.x;
  int beg = offs[n], end = offs[n+1];
  float4 sln = *((const float4*)(sl + (size_t)n*4));
  float m0=-1e30f,m1=-1e30f,m2=-1e30f,m3=-1e30f;
  for(int j=beg+lane; j<end; j+=64){
    int s = srcs[j];
    float4 a = *((const float4*)(sr + (size_t)s*4));
    m0 = fmaxf(m0, lrelu(sln.x + a.x));
    m1 = fmaxf(m1, lrelu(sln.y + a.y));
    m2 = fmaxf(m2, lrelu(sln.z + a.z));
    m3 = fmaxf(m3, lrelu(sln.w + a.w));
  }
  #pragma unroll
  for(int o=32;o>0;o>>=1){
    m0 = fmaxf(m0, __shfl_xor(m0,o));
    m1 = fmaxf(m1, __shfl_xor(m1,o));
    m2 = fmaxf(m2, __shfl_xor(m2,o));
    m3 = fmaxf(m3, __shfl_xor(m3,o));
  }
  int h0 = lane >> 5;
  float den0=0.f,den1=0.f,den2=0.f,den3=0.f;
  float acc0=0.f, acc1=0.f;
  for(int c0=beg; c0<end; c0+=64){
    int cnt = min(64, end-c0);
    int j = c0 + lane;
    float e0=0.f,e1=0.f,e2=0.f,e3=0.f, wd=0.f; int s=0;
    if(j<end){
      s = srcs[j];
      float4 a = *((const float4*)(sr + (size_t)s*4));
      e0 = __expf(lrelu(sln.x + a.x) - m0);
      e1 = __expf(lrelu(sln.y + a.y) - m1);
      e2 = __expf(lrelu(sln.z + a.z) - m2);
      e3 = __expf(lrelu(sln.w + a.w) - m3);
      wd = dinv[s];
    }
    den0+=e0; den1+=e1; den2+=e2; den3+=e3;
    s_sh[lane] = s;
    w_sh[lane*4+0] = wd*e0;
    w_sh[lane*4+1] = wd*e1;
    w_sh[lane*4+2] = wd*e2;
    w_sh[lane*4+3] = wd*e3;
    __syncthreads();
    int k = 0;
    for(; k+8<=cnt; k+=8){
      int sk[8];
      #pragma unroll
      for(int u=0;u<8;u++) sk[u] = __builtin_amdgcn_readfirstlane(s_sh[k+u]);
      unsigned pv[8];
      #pragma unroll
      for(int u=0;u<8;u++) pv[u] = xtb[(size_t)sk[u]*64 + lane];
      #pragma unroll
      for(int u=0;u<8;u++){
        float2 wv = *((const float2*)&w_sh[(k+u)*4 + h0*2]);
        acc0 += wv.x * __uint_as_float(pv[u] << 16);
        acc1 += wv.y * __uint_as_float(pv[u] & 0xffff0000u);
      }
    }
    for(; k<cnt; k++){
      int sk = __builtin_amdgcn_readfirstlane(s_sh[k]);
      unsigned pvv = xtb[(size_t)sk*64 + lane];
      float2 wv = *((const float2*)&w_sh[k*4 + h0*2]);
      acc0 += wv.x * __uint_as_float(pvv << 16);
      acc1 += wv.y * __uint_as_float(pvv & 0xffff0000u);
    }
    __syncthreads();
  }
  #pragma unroll
  for(int o=32;o>0;o>>=1){
    den0 += __shfl_xor(den0,o);
    den1 += __shfl_xor(den1,o);
    den2 += __shfl_xor(den2,o);
    den3 += __shfl_xor(den3,o);
  }
  float din = dinv[n];
  int ch0 = (lane < 32) ? lane : lane + 32;   // pairs (c, c+32)
  int ch1 = ch0 + 32;
  float d0 = (lane < 32) ? den0 : den2;
  float d1 = (lane < 32) ? den1 : den3;
  float o0 = din*acc0/(d0 + 1e-16f) + b1[ch0];
  float o1 = din*acc1/(d1 + 1e-16f) + b1[ch1];
  h[(size_t)n*128 + ch0] = o0 > 0.f ? o0 : 0.f;
  h[(size_t)n*128 + ch1] = o1 > 0.f ? o1 : 0.f;
}

// ---------------- layer 2 GEMM (128->16) + attention scalars, bf16-pair payload ----------------

__global__ __launch_bounds__(256) void k_gemm2(const float* __restrict__ hmat, const float* __restrict__ W2,
    const float* __restrict__ att2, unsigned* __restrict__ xt2b,
    float* __restrict__ sl2, float* __restrict__ sr2, int N){
  __shared__ float hs[16*132];
  __shared__ float ws[16*132];
  __shared__ float xs[16*16];
  int t = threadIdx.x;
  int n0 = blockIdx.x * 16;
  #pragma unroll
  for(int i=0;i<8;i++){
    int idx = t + 256*i;
    int k = idx >> 4, c = idx & 15;
    ws[c*132 + k] = W2[idx];
  }
  #pragma unroll
  for(int i=0;i<2;i++){
    int idx = t + 256*i;
    int r = idx >> 5, k4 = idx & 31;
    int n = n0 + r;
    float4 v = make_float4(0.f,0.f,0.f,0.f);
    if(n < N) v = ((const float4*)hmat)[(size_t)n*32 + k4];
    *((float4*)&hs[r*132 + k4*4]) = v;
  }
  __syncthreads();
  int r = t >> 4, c = t & 15;
  float acc = 0.f;
  for(int k=0;k<128;k+=4){
    float4 hv = *((const float4*)&hs[r*132+k]);
    float4 wv = *((const float4*)&ws[c*132+k]);
    acc += hv.x*wv.x + hv.y*wv.y + hv.z*wv.z + hv.w*wv.w;
  }
  xs[r*16 + c] = acc;
  __syncthreads();
  int n = n0 + r;
  if(c < 8 && n < N){
    unsigned pk = (unsigned)bfr(xs[r*16+c]) | ((unsigned)bfr(xs[r*16+c+8])<<16);
    xt2b[(size_t)n*8 + c] = pk;
  }
  if(t < 16){
    int nn = n0 + t;
    if(nn < N){
      float a = 0.f, b = 0.f;
      #pragma unroll
      for(int cc=0;cc<16;cc++){ float v = xs[t*16+cc]; a += v*att2[cc]; b += v*att2[16+cc]; }
      sl2[nn] = a; sr2[nn] = b;
    }
  }
}

// ---------------- layer 2 aggregation: 8 edge-groups x 8 channel-lanes ----------------

__global__ __launch_bounds__(64) void k_agg2(const int* __restrict__ offs, const int* __restrict__ srcs,
    const float* __restrict__ sl2, const float* __restrict__ sr2, const float* __restrict__ dinv,
    const unsigned* __restrict__ xt2b, const float* __restrict__ b2, float* __restrict__ out, int N){
  __shared__ int   s_sh[64];
  __shared__ float w_sh[64];
  int n = blockIdx.x;
  if(n >= N) return;
  int lane = threadIdx.x;
  int beg = offs[n], end = offs[n+1];
  float sln = sl2[n];
  float m = -1e30f;
  for(int j=beg+lane; j<end; j+=64)
    m = fmaxf(m, lrelu(sln + sr2[srcs[j]]));
  #pragma unroll
  for(int o=32;o>0;o>>=1) m = fmaxf(m, __shfl_xor(m,o));
  float den = 0.f, acc0 = 0.f, acc1 = 0.f;
  int grp = lane >> 3, ch = lane & 7;
  for(int c0=beg; c0<end; c0+=64){
    int cnt = min(64, end-c0);
    int j = c0 + lane;
    float e=0.f, wd=0.f; int s=0;
    if(j<end){
      s = srcs[j];
      e = __expf(lrelu(sln + sr2[s]) - m);
      wd = dinv[s];
    }
    den += e;
    s_sh[lane] = s;
    w_sh[lane] = wd*e;
    __syncthreads();
    for(int k=0;k<cnt;k+=8){
      int kk = k + grp;
      if(kk < cnt){
        int sk = s_sh[kk];
        float wk = w_sh[kk];
        unsigned pv = xt2b[(size_t)sk*8 + ch];
        acc0 += wk * __uint_as_float(pv << 16);
        acc1 += wk * __uint_as_float(pv & 0xffff0000u);
      }
    }
    __syncthreads();
  }
  #pragma unroll
  for(int o=32;o>0;o>>=1) den += __shfl_xor(den,o);
  acc0 += __shfl_xor(acc0,8);  acc0 += __shfl_xor(acc0,16);  acc0 += __shfl_xor(acc0,32);
  acc1 += __shfl_xor(acc1,8);  acc1 += __shfl_xor(acc1,16);  acc1 += __shfl_xor(acc1,32);
  if(lane < 8){
    float din = dinv[n];
    out[(size_t)n*16 + lane]     = din*acc0/(den + 1e-16f) + b2[lane];
    out[(size_t)n*16 + lane + 8] = din*acc1/(den + 1e-16f) + b2[lane+8];
  }
}

// ---------------- host launch ----------------

extern "C" void kernel_launch(void* const* d_in, const int* in_sizes, int n_in,
                              void* d_out, int out_size, void* d_ws, size_t ws_size,
                              hipStream_t stream){
  const float* x    = (const float*)d_in[0];
  const int*   ei   = (const int*)d_in[1];
  const float* W1   = (const float*)d_in[2];
  const float* att1 = (const float*)d_in[3];
  const float* b1   = (const float*)d_in[4];
  const float* W2   = (const float*)d_in[5];
  const float* att2 = (const float*)d_in[6];
  const float* b2   = (const float*)d_in[7];
  int N = in_sizes[0] / 256;
  int E = in_sizes[1] / 2;
  const int* rows = ei;
  const int* cols = ei + E;
  float* out = (float*)d_out;

  int ET   = E + N;
  int CS   = (ET + NCHUNK - 1) / NCHUNK;          // rank16 fits u16 iff CS < 65536
  int NSEG = (N + SEGSZ - 1) >> SEGSH;

  char* p = (char*)d_ws;
  auto alloc = [&](size_t bytes)->void*{ void* q = p; p += (bytes + 255) & ~(size_t)255; return q; };
  int*      cnt     = (int*)alloc((size_t)N*4);
  int*      offs    = (int*)alloc((size_t)(N+1)*4);
  int*      bsum    = (int*)alloc(256*4);
  int*      csr     = (int*)alloc((size_t)ET*4);
  float*    dinv    = (float*)alloc((size_t)N*4);
  float*    xt1     = (float*)alloc((size_t)N*128*4);
  unsigned* xtb     = (unsigned*)alloc((size_t)N*64*4);
  float*    sl1     = (float*)alloc((size_t)N*16);
  float*    sr1     = (float*)alloc((size_t)N*16);
  float*    hbuf    = (float*)alloc((size_t)N*128*4);
  unsigned* xt2b    = (unsigned*)alloc((size_t)N*8*4);
  float*    sl2     = (float*)alloc((size_t)N*4);
  float*    sr2     = (float*)alloc((size_t)N*4);
  short*    Whi     = (short*)alloc((size_t)128*256*2);
  short*    Wlo     = (short*)alloc((size_t)128*256*2);

  // transient graph-build slabs alias NN buffers written only later in the stream:
  int*            partial_d = (int*)xt1;               // 28.7MB <= 51.2MB, consumed before k_gemm1
  int*            partial_c = (int*)hbuf;              // consumed (k_fill2) before k_agg1 writes hbuf
  unsigned short* rank16    = (unsigned short*)xtb;    // consumed before k_gemm1 writes xtb

  int gN = (N + TPB - 1) / TPB;
  int NB = (N + 1023) / 1024;

  k_hist<false><<<NSEG*NCHUNK, 256, 0, stream>>>(rows, nullptr, partial_d, E, N, ET, CS);
  k_hist<true ><<<NSEG*NCHUNK, 256, 0, stream>>>(cols, rank16,  partial_c, E, N, ET, CS);
  k_red2<<<gN, TPB, 0, stream>>>(partial_d, partial_c, cnt, dinv, N);
  k_scan_block<<<NB, 256, 0, stream>>>(cnt, bsum, N);
  k_scan_bsum<<<1, 256, 0, stream>>>(bsum, NB);
  k_scan_write<<<NB, 256, 0, stream>>>(cnt, bsum, offs, N);
  k_rebase<<<gN, TPB, 0, stream>>>(partial_c, offs, N);
  k_fill2<<<(ET + TPB - 1)/TPB, TPB, 0, stream>>>(rows, cols, rank16, partial_c, csr, E, N, ET, CS);

  k_prepW<<<128, 256, 0, stream>>>(W1, Whi, Wlo);
  k_gemm1<<<(N + 127)/128, 256, 0, stream>>>(x, Whi, Wlo, xt1, xtb, N);
  k_sr1<<<(4*N + TPB - 1)/TPB, TPB, 0, stream>>>(xt1, att1, sl1, sr1, N);
  k_agg1<<<N, 64, 0, stream>>>(offs, csr, sl1, sr1, dinv, xtb, b1, hbuf, N);

  k_gemm2<<<(N + 15)/16, 256, 0, stream>>>(hbuf, W2, att2, xt2b, sl2, sr2, N);
  k_agg2<<<N, 64, 0, stream>>>(offs, csr, sl2, sr2, dinv, xt2b, b2, out, N);
}